// Round 17
// baseline (230.114 us; speedup 1.0000x reference)
//
#include <hip/hip_runtime.h>
#include <math.h>

#define NTOK 1024
#define DIMM 512
#define NH 8
#define HD 64
#define BCB 16
#define BSB 16
#define KSEL 8
#define WWIN 256
#define CBLK 64
#define SCALE 0.125f
#define EPSV 1e-6f
#define NEGV -1e30f

typedef short bf16x8 __attribute__((ext_vector_type(8)));
typedef float f32x4 __attribute__((ext_vector_type(4)));

__device__ inline ushort f2b(float f) {
  union { float f; unsigned int u; } c; c.f = f;
  unsigned int u = c.u;
  return (ushort)((u + 0x7FFFu + ((u >> 16) & 1u)) >> 16);
}
__device__ inline float b2f(ushort h) {
  union { unsigned int u; float f; } c; c.u = ((unsigned int)h) << 16;
  return c.f;
}

__device__ inline float wred_max(float v) {
#pragma unroll
  for (int off = 1; off < 64; off <<= 1) v = fmaxf(v, __shfl_xor(v, off));
  return v;
}
__device__ inline float wred_sum(float v) {
#pragma unroll
  for (int off = 1; off < 64; off <<= 1) v += __shfl_xor(v, off);
  return v;
}

// ---------- roots: weight transposes + resid/rms + trig tables + pos@W ----------
struct WtrDesc { const float* src; ushort* dh; ushort* dl; int K; int Nsrc; int Npad; };
struct WtrPack { WtrDesc d[9]; int cum[9]; };

__global__ void __launch_bounds__(256)
k_pre(WtrPack pk, const float* __restrict__ x, const float* __restrict__ x0,
      const float* __restrict__ lam, float* __restrict__ xr,
      ushort* __restrict__ xnh, ushort* __restrict__ xnl,
      float* __restrict__ ctab, float* __restrict__ stab,
      const float* __restrict__ k_pos, const float* __restrict__ v_pos,
      const float* __restrict__ Wck, const float* __restrict__ Wcv,
      const float* __restrict__ bck, const float* __restrict__ bcv,
      float* __restrict__ pwk, float* __restrict__ pwv) {
  __shared__ float t[32][33];
  __shared__ float sm[8];
  __shared__ float red[4][64];
  int bid = blockIdx.x, tid = threadIdx.x;
  if (bid < pk.cum[8]) {
    // ---- weight transpose (f32 K x N -> bf16 hi/lo N x K) ----
    int gb = bid;
    int e = 0;
    while (gb >= pk.cum[e]) e++;
    int start = e ? pk.cum[e - 1] : 0;
    WtrDesc dd = pk.d[e];
    int local = gb - start;
    int XT = dd.Npad >> 5;
    int bx = local % XT, by = local / XT;
    int n0 = bx * 32, k0 = by * 32;
    int tx = tid & 31, ty = tid >> 5;
#pragma unroll
    for (int i = 0; i < 32; i += 8)
      t[ty + i][tx] = (n0 + tx < dd.Nsrc)
          ? dd.src[(size_t)(k0 + ty + i) * dd.Nsrc + n0 + tx] : 0.f;
    __syncthreads();
#pragma unroll
    for (int i = 0; i < 32; i += 8) {
      float vv = t[tx][ty + i];
      ushort h = f2b(vv);
      size_t di = (size_t)(n0 + ty + i) * dd.K + k0 + tx;
      dd.dh[di] = h;
      if (dd.dl) dd.dl[di] = f2b(vv - b2f(h));
    }
  } else if (bid < pk.cum[8] + NTOK) {
    // ---- residual mix + rmsnorm, bf16 hi/lo out ----
    int row = bid - pk.cum[8];
    float l0 = lam[0], l1 = lam[1];
    size_t b = (size_t)row * DIMM;
    float a0 = l0 * x[b + tid]       + l1 * x0[b + tid];
    float a1 = l0 * x[b + tid + 256] + l1 * x0[b + tid + 256];
    xr[b + tid] = a0; xr[b + tid + 256] = a1;
    float ss = a0 * a0 + a1 * a1;
    for (int o = 32; o > 0; o >>= 1) ss += __shfl_down(ss, o);
    int lane = tid & 63, wid = tid >> 6;
    if (lane == 0) sm[wid] = ss;
    __syncthreads();
    if (tid == 0) {
      float s = sm[0] + sm[1] + sm[2] + sm[3];
      sm[0] = rsqrtf(s / (float)DIMM + EPSV);
    }
    __syncthreads();
    float r = sm[0];
    float v0 = a0 * r, v1 = a1 * r;
    ushort h0 = f2b(v0), h1 = f2b(v1);
    xnh[b + tid] = h0;        xnh[b + tid + 256] = h1;
    xnl[b + tid] = f2b(v0 - b2f(h0));
    xnl[b + tid + 256] = f2b(v1 - b2f(h1));
  } else if (bid < pk.cum[8] + NTOK + 128) {
    // ---- RoPE cos/sin tables: [n][d<32] ----
    int g = (bid - pk.cum[8] - NTOK) * 256 + tid;
    int n = g >> 5, d = g & 31;
    float inv = powf(10000.f, -(float)d / 32.f);
    float sn, cs;
    sincosf((float)n * inv, &sn, &cs);
    ctab[g] = cs; stab[g] = sn;
  } else {
    // ---- pw[h][d] = pos[h]@W + bias (16 blocks: (kv,h)) ----
    int idx2 = bid - pk.cum[8] - NTOK - 128;
    int h = idx2 & 7, kv = idx2 >> 3;
    const float* pos = kv ? v_pos : k_pos;
    const float* W = kv ? Wcv : Wck;
    const float* bias = kv ? bcv : bck;
    float* pw = kv ? pwv : pwk;
    int d = tid & 63, part = tid >> 6;
    float s = 0.f;
    for (int i = 0; i < 256; i++) {
      int kk = part * 256 + i;
      s += pos[h * 1024 + kk] * W[(size_t)kk * 64 + d];
    }
    red[part][d] = s;
    __syncthreads();
    if (part == 0)
      pw[h * 64 + d] = red[0][d] + red[1][d] + red[2][d] + red[3][d] + bias[d];
  }
}

// ---------- fused Wo-combine + rmsnorm: out = xr+p0+p1 ; y = bf16(rms(out)) ----------
__global__ void __launch_bounds__(256)
k_rms_bf(const float* __restrict__ xr, const float* __restrict__ p0,
         const float* __restrict__ p1, float* __restrict__ outb,
         ushort* __restrict__ y) {
  int row = blockIdx.x, tid = threadIdx.x;
  size_t b = (size_t)row * DIMM;
  float a0 = xr[b + tid]       + p0[b + tid]       + p1[b + tid];
  float a1 = xr[b + tid + 256] + p0[b + tid + 256] + p1[b + tid + 256];
  outb[b + tid] = a0; outb[b + tid + 256] = a1;
  float ss = a0 * a0 + a1 * a1;
  __shared__ float sm[8];
  for (int o = 32; o > 0; o >>= 1) ss += __shfl_down(ss, o);
  int lane = tid & 63, wid = tid >> 6;
  if (lane == 0) sm[wid] = ss;
  __syncthreads();
  if (tid == 0) {
    float s = sm[0] + sm[1] + sm[2] + sm[3];
    sm[0] = rsqrtf(s / (float)DIMM + EPSV);
  }
  __syncthreads();
  float r = sm[0];
  y[b + tid] = f2b(a0 * r); y[b + tid + 256] = f2b(a1 * r);
}

// ---------- W1 GEMM: 64x64 tile (grid 512 = 2/CU; was 256 = grid-bound), relu^2 -> bf16 ----------
__global__ void __launch_bounds__(256)
k_gemm_w1(const ushort* __restrict__ A, const ushort* __restrict__ BT,
          ushort* __restrict__ Co) {
  const int Kd = 512, Nd = 2048;
  __shared__ ushort As[64 * 40];
  __shared__ ushort Bs[64 * 40];
  int tid = threadIdx.x;
  int lane = tid & 63, w = tid >> 6;
  int rb = blockIdx.y * 64, cb = blockIdx.x * 64;
  int wm = (w >> 1) * 32, wn = (w & 1) * 32;
  int quad = lane >> 4, l15 = lane & 15;
  int srow = tid >> 2, scol = (tid & 3) * 8;

  f32x4 acc[2][2];
#pragma unroll
  for (int i = 0; i < 2; i++)
#pragma unroll
    for (int j = 0; j < 2; j++) acc[i][j] = (f32x4){0.f, 0.f, 0.f, 0.f};

  const ushort* ap = A  + (size_t)(rb + srow) * Kd + scol;
  const ushort* bp = BT + (size_t)(cb + srow) * Kd + scol;
  ushort* aw = &As[srow * 40 + scol];
  ushort* bw = &Bs[srow * 40 + scol];

  int4 pa = *(const int4*)ap;
  int4 pb = *(const int4*)bp;

  for (int k0 = 0; k0 < Kd; k0 += 32) {
    if (k0) __syncthreads();
    *(int4*)aw = pa;
    *(int4*)bw = pb;
    __syncthreads();
    if (k0 + 32 < Kd) {
      pa = *(const int4*)(ap + k0 + 32);
      pb = *(const int4*)(bp + k0 + 32);
    }
    bf16x8 af[2], bfr[2];
#pragma unroll
    for (int t = 0; t < 2; t++) {
      af[t]  = *(const bf16x8*)&As[(wm + t * 16 + l15) * 40 + quad * 8];
      bfr[t] = *(const bf16x8*)&Bs[(wn + t * 16 + l15) * 40 + quad * 8];
    }
#pragma unroll
    for (int i = 0; i < 2; i++)
#pragma unroll
      for (int j = 0; j < 2; j++)
        acc[i][j] = __builtin_amdgcn_mfma_f32_16x16x32_bf16(af[i], bfr[j],
                                                            acc[i][j], 0, 0, 0);
  }

#pragma unroll
  for (int i = 0; i < 2; i++) {
#pragma unroll
    for (int j = 0; j < 2; j++) {
      int col = cb + wn + j * 16 + l15;
#pragma unroll
      for (int r = 0; r < 4; r++) {
        int row = rb + wm + i * 16 + quad * 4 + r;
        float t = fmaxf(acc[i][j][r], 0.f);
        Co[(size_t)row * Nd + col] = f2b(t * t);
      }
    }
  }
}

// ---------- W2 GEMM: 64x64 tile, split-K=4 (grid 512 = 2/CU), atomicAdd into out ----------
__global__ void __launch_bounds__(256)
k_gemm_w2(const ushort* __restrict__ A, const ushort* __restrict__ BT,
          float* __restrict__ outb) {
  const int Kd = 2048;
  __shared__ ushort As[64 * 40];
  __shared__ ushort Bs[64 * 40];
  int tid = threadIdx.x;
  int lane = tid & 63, w = tid >> 6;
  int rb = blockIdx.y * 64, cb = blockIdx.x * 64;
  int kb = blockIdx.z * 512;
  int wm = (w >> 1) * 32, wn = (w & 1) * 32;
  int quad = lane >> 4, l15 = lane & 15;
  int srow = tid >> 2, scol = (tid & 3) * 8;

  f32x4 acc[2][2];
#pragma unroll
  for (int i = 0; i < 2; i++)
#pragma unroll
    for (int j = 0; j < 2; j++) acc[i][j] = (f32x4){0.f, 0.f, 0.f, 0.f};

  const ushort* ap = A  + (size_t)(rb + srow) * Kd + kb + scol;
  const ushort* bp = BT + (size_t)(cb + srow) * Kd + kb + scol;
  ushort* aw = &As[srow * 40 + scol];
  ushort* bw = &Bs[srow * 40 + scol];

  int4 pa = *(const int4*)ap;
  int4 pb = *(const int4*)bp;

  for (int k0 = 0; k0 < 512; k0 += 32) {
    if (k0) __syncthreads();
    *(int4*)aw = pa;
    *(int4*)bw = pb;
    __syncthreads();
    if (k0 + 32 < 512) {
      pa = *(const int4*)(ap + k0 + 32);
      pb = *(const int4*)(bp + k0 + 32);
    }
    bf16x8 af[2], bfr[2];
#pragma unroll
    for (int t = 0; t < 2; t++) {
      af[t]  = *(const bf16x8*)&As[(wm + t * 16 + l15) * 40 + quad * 8];
      bfr[t] = *(const bf16x8*)&Bs[(wn + t * 16 + l15) * 40 + quad * 8];
    }
#pragma unroll
    for (int i = 0; i < 2; i++)
#pragma unroll
      for (int j = 0; j < 2; j++)
        acc[i][j] = __builtin_amdgcn_mfma_f32_16x16x32_bf16(af[i], bfr[j],
                                                            acc[i][j], 0, 0, 0);
  }

#pragma unroll
  for (int i = 0; i < 2; i++) {
#pragma unroll
    for (int j = 0; j < 2; j++) {
      int col = cb + wn + j * 16 + l15;
#pragma unroll
      for (int r = 0; r < 4; r++) {
        int row = rb + wm + i * 16 + quad * 4 + r;
        atomicAdd(&outb[(size_t)row * 512 + col], acc[i][j][r]);
      }
    }
  }
}

// ---------- Wo GEMM, split-K=2, fused gated combine in A-staging; partials out ----------
__global__ void __launch_bounds__(256)
k_gemm_wo(const float* __restrict__ cg, const float* __restrict__ fg,
          const float* __restrict__ sg, const float* __restrict__ gates,
          const ushort* __restrict__ BT, float* __restrict__ P0,
          float* __restrict__ P1) {
  __shared__ ushort As[64 * 40];
  __shared__ ushort Bs[64 * 40];
  int tid = threadIdx.x;
  int lane = tid & 63, wave = tid >> 6;
  int rb = blockIdx.y * 64, cb = blockIdx.x * 64;
  int kb = blockIdx.z * 256;
  int wm = (wave >> 1) * 32, wn = (wave & 1) * 32;
  int q = lane >> 4, l15 = lane & 15;
  int srow = tid >> 2, scol = (tid & 3) * 8;

  f32x4 acc[2][2];
#pragma unroll
  for (int i = 0; i < 2; i++)
#pragma unroll
    for (int j = 0; j < 2; j++) acc[i][j] = (f32x4){0.f, 0.f, 0.f, 0.f};

  int row = rb + srow;
  const ushort* bp = BT + (size_t)(cb + srow) * 512 + kb + scol;
  ushort* aw = &As[srow * 40 + scol];
  ushort* bw = &Bs[srow * 40 + scol];

  for (int k0 = 0; k0 < 256; k0 += 32) {
    int colb = kb + k0 + scol;
    int hh = colb >> 6;
    const float* gp = gates + (size_t)row * 24 + hh * 3;
    float g0 = gp[0], g1 = gp[1], g2 = gp[2];
    size_t off = (size_t)row * 512 + colb;
    float4 c0 = *(const float4*)(cg + off), c1 = *(const float4*)(cg + off + 4);
    float4 f0 = *(const float4*)(fg + off), f1 = *(const float4*)(fg + off + 4);
    float4 s0 = *(const float4*)(sg + off), s1 = *(const float4*)(sg + off + 4);
    float va[8] = {g0 * c0.x + g1 * f0.x + g2 * s0.x,
                   g0 * c0.y + g1 * f0.y + g2 * s0.y,
                   g0 * c0.z + g1 * f0.z + g2 * s0.z,
                   g0 * c0.w + g1 * f0.w + g2 * s0.w,
                   g0 * c1.x + g1 * f1.x + g2 * s1.x,
                   g0 * c1.y + g1 * f1.y + g2 * s1.y,
                   g0 * c1.z + g1 * f1.z + g2 * s1.z,
                   g0 * c1.w + g1 * f1.w + g2 * s1.w};
    ushort h[8];
#pragma unroll
    for (int e = 0; e < 8; e++) h[e] = f2b(va[e]);
    *(int4*)aw = *(int4*)h;
    *(int4*)bw = *(const int4*)(bp + k0);
    __syncthreads();
    bf16x8 af[2], bfr[2];
#pragma unroll
    for (int t = 0; t < 2; t++) {
      af[t]  = *(const bf16x8*)&As[(wm + t * 16 + l15) * 40 + q * 8];
      bfr[t] = *(const bf16x8*)&Bs[(wn + t * 16 + l15) * 40 + q * 8];
    }
#pragma unroll
    for (int i = 0; i < 2; i++)
#pragma unroll
      for (int j = 0; j < 2; j++)
        acc[i][j] = __builtin_amdgcn_mfma_f32_16x16x32_bf16(af[i], bfr[j],
                                                            acc[i][j], 0, 0, 0);
    __syncthreads();
  }

  float* pbuf = blockIdx.z ? P1 : P0;
#pragma unroll
  for (int i = 0; i < 2; i++) {
#pragma unroll
    for (int j = 0; j < 2; j++) {
      int col = cb + wn + j * 16 + l15;
#pragma unroll
      for (int r = 0; r < 4; r++) {
        int rr = rb + wm + i * 16 + q * 4 + r;
        pbuf[(size_t)rr * 512 + col] = acc[i][j][r];
      }
    }
  }
}

// ---------- QKV GEMM 128Mx64N with fused RoPE + bf16 hi/lo k/v mirrors + gates ----------
__global__ void __launch_bounds__(256)
k_gemm_qkv(const ushort* __restrict__ Ah, const ushort* __restrict__ Al,
           const ushort* __restrict__ BTh, const ushort* __restrict__ BTl,
           float* __restrict__ qout, ushort* __restrict__ khm_h,
           ushort* __restrict__ khm_l, ushort* __restrict__ vhm_h,
           ushort* __restrict__ vhm_l, float* __restrict__ gates,
           const float* __restrict__ ctab, const float* __restrict__ stab) {
  const int Kd = 512;
  __shared__ ushort SM[15360];   // Ash 128x40 | Asl 128x40 | Bsh 64x40 | Bsl 64x40
  ushort* Ash = SM;
  ushort* Asl = SM + 5120;
  ushort* Bsh = SM + 10240;
  ushort* Bsl = SM + 12800;
  int tid = threadIdx.x;
  int lane = tid & 63, wave = tid >> 6;
  int rb = blockIdx.y * 128, cb = blockIdx.x * 64;
  const bool prec = (cb < 1024);   // q/k columns need f32-grade (selection)
  int wm = (wave >> 1) * 64, wn = (wave & 1) * 32;
  int q = lane >> 4, l15 = lane & 15;
  int srA = tid >> 1, scA = (tid & 1) * 16;
  int srB = tid >> 2, scB = (tid & 3) * 8;

  f32x4 acc[4][2];
#pragma unroll
  for (int i = 0; i < 4; i++)
#pragma unroll
    for (int j = 0; j < 2; j++) acc[i][j] = (f32x4){0.f, 0.f, 0.f, 0.f};

  const ushort* aph = Ah  + (size_t)(rb + srA) * Kd + scA;
  const ushort* apl = Al  + (size_t)(rb + srA) * Kd + scA;
  const ushort* bph = BTh + (size_t)(cb + srB) * Kd + scB;
  const ushort* bpl = BTl + (size_t)(cb + srB) * Kd + scB;
  ushort* awh = &Ash[srA * 40 + scA];
  ushort* awl = &Asl[srA * 40 + scA];
  ushort* bwh = &Bsh[srB * 40 + scB];
  ushort* bwl = &Bsl[srB * 40 + scB];

  int4 ph0 = *(const int4*)aph;
  int4 ph1 = *(const int4*)(aph + 8);
  int4 pbh = *(const int4*)bph;
  int4 pl0, pl1, pbl;
  if (prec) {
    pl0 = *(const int4*)apl;
    pl1 = *(const int4*)(apl + 8);
    pbl = *(const int4*)bpl;
  }

  for (int k0 = 0; k0 < Kd; k0 += 32) {
    if (k0) __syncthreads();
    *(int4*)awh = ph0; *(int4*)(awh + 8) = ph1;
    *(int4*)bwh = pbh;
    if (prec) {
      *(int4*)awl = pl0; *(int4*)(awl + 8) = pl1;
      *(int4*)bwl = pbl;
    }
    __syncthreads();
    if (k0 + 32 < Kd) {
      ph0 = *(const int4*)(aph + k0 + 32);
      ph1 = *(const int4*)(aph + k0 + 40);
      pbh = *(const int4*)(bph + k0 + 32);
      if (prec) {
        pl0 = *(const int4*)(apl + k0 + 32);
        pl1 = *(const int4*)(apl + k0 + 40);
        pbl = *(const int4*)(bpl + k0 + 32);
      }
    }
    bf16x8 afh[4], bfh[2], afl[4], bfl[2];
#pragma unroll
    for (int t = 0; t < 4; t++)
      afh[t] = *(const bf16x8*)&Ash[(wm + t * 16 + l15) * 40 + q * 8];
#pragma unroll
    for (int t = 0; t < 2; t++)
      bfh[t] = *(const bf16x8*)&Bsh[(wn + t * 16 + l15) * 40 + q * 8];
    if (prec) {
#pragma unroll
      for (int t = 0; t < 4; t++)
        afl[t] = *(const bf16x8*)&Asl[(wm + t * 16 + l15) * 40 + q * 8];
#pragma unroll
      for (int t = 0; t < 2; t++)
        bfl[t] = *(const bf16x8*)&Bsl[(wn + t * 16 + l15) * 40 + q * 8];
    }
#pragma unroll
    for (int i = 0; i < 4; i++)
#pragma unroll
      for (int j = 0; j < 2; j++) {
        acc[i][j] = __builtin_amdgcn_mfma_f32_16x16x32_bf16(afh[i], bfh[j],
                                                            acc[i][j], 0, 0, 0);
        if (prec) {
          acc[i][j] = __builtin_amdgcn_mfma_f32_16x16x32_bf16(afh[i], bfl[j],
                                                              acc[i][j], 0, 0, 0);
          acc[i][j] = __builtin_amdgcn_mfma_f32_16x16x32_bf16(afl[i], bfh[j],
                                                              acc[i][j], 0, 0, 0);
        }
      }
  }

  if (prec) {
    // ---- fused RoPE epilogue: two 64-row half-passes via LDS overlay ----
    float* st = (float*)SM;   // 64 x 66 f32 = 16896 B (fits in 30720 B)
    int h = (cb & 511) >> 6;
#pragma unroll
    for (int hb = 0; hb < 2; hb++) {
      __syncthreads();
      if ((wave >> 1) == hb) {
#pragma unroll
        for (int i = 0; i < 4; i++)
#pragma unroll
          for (int j = 0; j < 2; j++)
#pragma unroll
            for (int r = 0; r < 4; r++)
              st[(i * 16 + q * 4 + r) * 66 + wn + j * 16 + l15] = acc[i][j][r];
      }
      __syncthreads();
#pragma unroll
      for (int e = 0; e < 8; e++) {
        int p = e * 256 + tid;          // 2048 pairs: 64 rows x 32 dims
        int rw = p >> 5, d = p & 31;
        int n = rb + hb * 64 + rw;
        float x1 = st[rw * 66 + d], x2 = st[rw * 66 + d + 32];
        float cs = ctab[n * 32 + d], sn = stab[n * 32 + d];
        float o1 = x1 * cs - x2 * sn;
        float o2 = x2 * cs + x1 * sn;
        if (cb < 512) {
          qout[(size_t)n * 512 + h * 64 + d]      = o1;
          qout[(size_t)n * 512 + h * 64 + d + 32] = o2;
        } else {
          size_t ob = (size_t)h * 65536 + (size_t)n * 64 + d;
          ushort b1 = f2b(o1), b2v = f2b(o2);
          khm_h[ob]      = b1;
          khm_h[ob + 32] = b2v;
          khm_l[ob]      = f2b(o1 - b2f(b1));
          khm_l[ob + 32] = f2b(o2 - b2f(b2v));
        }
      }
    }
  } else {
#pragma unroll
    for (int i = 0; i < 4; i++) {
#pragma unroll
      for (int j = 0; j < 2; j++) {
        int col = cb + wn + j * 16 + l15;
#pragma unroll
        for (int r = 0; r < 4; r++) {
          int row = rb + wm + i * 16 + q * 4 + r;
          float vv = acc[i][j][r];
          if (cb >= 1536) {
            int c24 = col - 1536;
            if (c24 < 24)
              gates[(size_t)row * 24 + c24] = 1.f / (1.f + expf(-vv));
          } else {
            int c = col - 1024;       // v plane -> head-major bf16 hi/lo
            size_t ob = (size_t)(c >> 6) * 65536 + (size_t)row * 64 + (c & 63);
            ushort hb = f2b(vv);
            vhm_h[ob] = hb;
            vhm_l[ob] = f2b(vv - b2f(hb));
          }
        }
      }
    }
  }
}

// ---------- merged: compressed k/v MFMA (blocks 0..31) || sliding-window flash (32..159) ----------
__global__ void __launch_bounds__(256)
k_mid(const ushort* __restrict__ khm_h, const ushort* __restrict__ khm_l,
      const ushort* __restrict__ vhm_h, const ushort* __restrict__ vhm_l,
      const ushort* __restrict__ WckTh, const ushort* __restrict__ WckTl,
      const ushort* __restrict__ WcvTh, const ushort* __restrict__ WcvTl,
      const float* __restrict__ pwk, const float* __restrict__ pwv,
      float* __restrict__ ckb, float* __restrict__ cvb,
      const float* __restrict__ qg, float* __restrict__ sout) {
  __shared__ union {
    struct { ushort Ash[32 * 72]; ushort Asl[32 * 72];
             ushort Bsh[64 * 72]; ushort Bsl[64 * 72]; } c;
    struct { ushort Kt[64 * 72]; ushort VT[64 * 72];
             ushort Qs[64 * 72]; ushort Ps[4][16 * 72]; } s;
  } U;
  int tid = threadIdx.x, lane = tid & 63, w = tid >> 6;
  int quad = lane >> 4, l15 = lane & 15;

  if (blockIdx.x < 32) {
    // ===== compressed k/v: pure int4 staging of pre-split hi/lo planes =====
    int h = blockIdx.x & 7, kv = (blockIdx.x >> 3) & 1, mh = blockIdx.x >> 4;
    const ushort* sH = kv ? vhm_h : khm_h;
    const ushort* sL = kv ? vhm_l : khm_l;
    const ushort* WTh = kv ? WcvTh : WckTh;
    const ushort* WTl = kv ? WcvTl : WckTl;
    const float* pw = (kv ? pwv : pwk) + h * 64;
    float* outp = kv ? cvb : ckb;

    ushort* Ash = U.c.Ash; ushort* Asl = U.c.Asl;
    ushort* Bsh = U.c.Bsh; ushort* Bsl = U.c.Bsl;
    int wmi = w >> 1, wnj = w & 1;
    int arow = tid >> 3, ae0 = (tid & 7) * 8;   // A: 32 rows x 64 cols
    int brow = tid >> 2, be0 = (tid & 3) * 16;  // B: 64 rows x 64 cols
    size_t abase = (size_t)h * 65536 + (size_t)(mh * 32 + arow) * 1024 + ae0;
    size_t bbase = (size_t)brow * 1024 + be0;

    f32x4 acc[2];
#pragma unroll
    for (int j = 0; j < 2; j++) acc[j] = (f32x4){0.f, 0.f, 0.f, 0.f};

    for (int t = 0; t < 16; t++) {
      int kb = t * 64;
      *(int4*)&Ash[arow * 72 + ae0] = *(const int4*)(sH + abase + kb);
      *(int4*)&Asl[arow * 72 + ae0] = *(const int4*)(sL + abase + kb);
      *(int4*)&Bsh[brow * 72 + be0]     = *(const int4*)(WTh + bbase + kb);
      *(int4*)&Bsh[brow * 72 + be0 + 8] = *(const int4*)(WTh + bbase + kb + 8);
      *(int4*)&Bsl[brow * 72 + be0]     = *(const int4*)(WTl + bbase + kb);
      *(int4*)&Bsl[brow * 72 + be0 + 8] = *(const int4*)(WTl + bbase + kb + 8);
      __syncthreads();
#pragma unroll
      for (int sub = 0; sub < 2; sub++) {
        int ar2 = (wmi * 16 + l15) * 72 + sub * 32 + quad * 8;
        bf16x8 afh = *(const bf16x8*)&Ash[ar2];
        bf16x8 afl = *(const bf16x8*)&Asl[ar2];
#pragma unroll
        for (int j = 0; j < 2; j++) {
          int br2 = (wnj * 32 + j * 16 + l15) * 72 + sub * 32 + quad * 8;
          bf16x8 bfh = *(const bf16x8*)&Bsh[br2];
          bf16x8 bfl = *(const bf16x8*)&Bsl[br2];
          acc[j] = __builtin_amdgcn_mfma_f32_16x16x32_bf16(afh, bfh, acc[j], 0, 0, 0);
          acc[j] = __builtin_amdgcn_mfma_f32_16x16x32_bf16(afh, bfl, acc[j], 0, 0, 0);
          acc[j] = __builtin_amdgcn_mfma_f32_16x16x32_bf16(afl, bfh, acc[j], 0, 0, 0);
        }
      }
      __syncthreads();
    }

#pragma unroll
    for (int j = 0; j < 2; j++) {
      int d = wnj * 32 + j * 16 + l15;
      float bv = pw[d];
#pragma unroll
      for (int r = 0; r < 4; r++) {
        int c = mh * 32 + wmi * 16 + quad * 4 + r;
        outp[((size_t)h * 64 + c) * 64 + d] = acc[j][r] + bv;
      }
    }
  } else {
    // ===== sliding window flash: 64 q-rows / 4 waves per block =====
    int sidx = blockIdx.x - 32;
    int h = sidx >> 4, i0 = (sidx & 15) * 64;
    ushort* Kt = U.s.Kt; ushort* VT = U.s.VT; ushort* Qs = U.s.Qs;

#pragma unroll
    for (int it = 0; it < 2; it++) {
      int f = it * 256 + tid;            // 512 chunks of 8 ushorts (64 rows)
      int r = f >> 3, d0 = (f & 7) * 8;
      const float* qp = qg + (size_t)(i0 + r) * DIMM + h * HD + d0;
      float4 t0 = *(const float4*)qp;
      float4 t1 = *(const float4*)(qp + 4);
      ushort u[8] = {f2b(t0.x), f2b(t0.y), f2b(t0.z), f2b(t0.w),
                     f2b(t1.x), f2b(t1.y), f2b(t1.z), f2b(t1.w)};
      *(int4*)&Qs[r * 72 + d0] = *(int4*)u;
    }

    int lo = i0 - (WWIN - 1); if (lo < 0) lo = 0;
    int jb_lo = lo >> 6, jb_hi = (i0 + 63) >> 6;

    float mrow[4], lrow[4];
    f32x4 Of[4];
#pragma unroll
    for (int r = 0; r < 4; r++) { mrow[r] = NEGV; lrow[r] = 0.f; }
#pragma unroll
    for (int d = 0; d < 4; d++) Of[d] = (f32x4){0.f, 0.f, 0.f, 0.f};

    for (int jb = jb_lo; jb <= jb_hi; jb++) {
      __syncthreads();
#pragma unroll
      for (int it = 0; it < 2; it++) {
        int f = it * 256 + tid;          // 512 chunks (64 rows)
        int r = f >> 3, c8 = (f & 7) * 8;
        const ushort* kp = khm_h + (size_t)h * 65536 + (size_t)(jb * 64 + r) * 64 + c8;
        *(int4*)&Kt[r * 72 + c8] = *(const int4*)kp;
        const ushort* vp = vhm_h + (size_t)h * 65536 + (size_t)(jb * 64 + r) * 64 + c8;
        ushort vv[8];
        *(int4*)vv = *(const int4*)vp;
#pragma unroll
        for (int e = 0; e < 8; e++) VT[(c8 + e) * 72 + r] = vv[e];
      }
      __syncthreads();

      bf16x8 qa[2];
#pragma unroll
      for (int c = 0; c < 2; c++)
        qa[c] = *(const bf16x8*)&Qs[(w * 16 + l15) * 72 + c * 32 + quad * 8];

      f32x4 sc[4];
      __builtin_amdgcn_s_setprio(1);
#pragma unroll
      for (int ks = 0; ks < 4; ks++) {
        f32x4 a = (f32x4){0.f, 0.f, 0.f, 0.f};
#pragma unroll
        for (int c = 0; c < 2; c++) {
          bf16x8 kb = *(const bf16x8*)&Kt[(ks * 16 + l15) * 72 + c * 32 + quad * 8];
          a = __builtin_amdgcn_mfma_f32_16x16x32_bf16(qa[c], kb, a, 0, 0, 0);
        }
        sc[ks] = a;
      }
      __builtin_amdgcn_s_setprio(0);

      float pm[4][4], rmax[4];
#pragma unroll
      for (int r = 0; r < 4; r++) rmax[r] = NEGV;
#pragma unroll
      for (int ks = 0; ks < 4; ks++) {
        int gj = jb * 64 + ks * 16 + l15;
#pragma unroll
        for (int r = 0; r < 4; r++) {
          int qi = i0 + w * 16 + quad * 4 + r;
          bool vis = (gj <= qi) && (qi - gj < WWIN);
          float s = vis ? sc[ks][r] * SCALE : NEGV;
          pm[ks][r] = s;
          rmax[r] = fmaxf(rmax[r], s);
        }
      }
#pragma unroll
      for (int off = 1; off < 16; off <<= 1)
#pragma unroll
        for (int r = 0; r < 4; r++)
          rmax[r] = fmaxf(rmax[r], __shfl_xor(rmax[r], off));

      float alpha[4], rsum[4];
#pragma unroll
      for (int r = 0; r < 4; r++) {
        float newm = fmaxf(mrow[r], rmax[r]);
        alpha[r] = expf(mrow[r] - newm);
        mrow[r] = newm;
        rsum[r] = 0.f;
      }
#pragma unroll
      for (int ks = 0; ks < 4; ks++)
#pragma unroll
        for (int r = 0; r < 4; r++) {
          float p = expf(pm[ks][r] - mrow[r]);
          pm[ks][r] = p;
          rsum[r] += p;
        }
#pragma unroll
      for (int off = 1; off < 16; off <<= 1)
#pragma unroll
        for (int r = 0; r < 4; r++)
          rsum[r] += __shfl_xor(rsum[r], off);
#pragma unroll
      for (int r = 0; r < 4; r++)
        lrow[r] = lrow[r] * alpha[r] + rsum[r];

#pragma unroll
      for (int ks = 0; ks < 4; ks++)
#pragma unroll
        for (int r = 0; r < 4; r++)
          U.s.Ps[w][(quad * 4 + r) * 72 + ks * 16 + l15] = f2b(pm[ks][r]);
#pragma unroll
      for (int d = 0; d < 4; d++)
#pragma unroll
        for (int r = 0; r < 4; r++)
          Of[d][r] *= alpha[r];

      __builtin_amdgcn_s_setprio(1);
#pragma unroll
      for (int c = 0; c < 2; c++) {
        bf16x8 pa = *(const bf16x8*)&U.s.Ps[w][l15 * 72 + c * 32 + quad * 8];
#pragma unroll
        for (int d = 0; d < 4; d++) {
          bf16x8 vb = *(const bf16x8*)&VT[(d * 16 + l15) * 72 + c * 32 + quad * 8];
          Of[d] = __builtin_amdgcn_mfma_f32_16x16x32_bf16(pa, vb, Of[d], 0, 0, 0);
        }
      }
      __builtin_amdgcn_s_setprio(0);
    }

#pragma unroll
    for (int d = 0; d < 4; d++)
#pragma unroll
      for (int r = 0; r < 4; r++) {
        int qi = i0 + w * 16 + quad * 4 + r;
        sout[(size_t)qi * DIMM + h * HD + d * 16 + l15] = Of[d][r] / lrow[r];
      }
  }
}

// ---------- fused: compressed attention + top-8 + fine attention (in-wave sel) ----------
// 4 q-rows/block, one row per wave; rank-based top-8 (replaces serial shuffle butterfly).
__global__ void __launch_bounds__(256)
k_cmpf(const float* __restrict__ qg, const float* __restrict__ ckb,
       const float* __restrict__ cvb, const float* __restrict__ k_mem,
       const float* __restrict__ v_mem, const ushort* __restrict__ khm_h,
       const ushort* __restrict__ vhm_h, float* __restrict__ cout,
       float* __restrict__ fout) {
  int h = blockIdx.y, i0 = blockIdx.x * 4;
  int tid = threadIdx.x, lane = tid & 63, w = tid >> 6;
  __shared__ float ckt[64][65];
  __shared__ float cvs[64][65];
  __shared__ float qs[4][64];
  __shared__ float kms[64], vms[64];
  __shared__ float sp[4][64];
  __shared__ float ivs[4][64];    // impv values for rank selection
  __shared__ int   sels[4][8];    // rank -> selected block index
  __shared__ float spf[4][144];   // fine p values, per wave

#pragma unroll
  for (int r = 0; r < 4; r++) {
    int f = r * 256 + tid;
    int c = f >> 4, d0 = (f & 15) * 4;
    float4 t = *(const float4*)(ckb + ((size_t)h * 64 + c) * 64 + d0);
    ckt[d0][c] = t.x; ckt[d0 + 1][c] = t.y; ckt[d0 + 2][c] = t.z; ckt[d0 + 3][c] = t.w;
    float4 u = *(const float4*)(cvb + ((size_t)h * 64 + c) * 64 + d0);
    cvs[c][d0] = u.x; cvs[c][d0 + 1] = u.y; cvs[c][d0 + 2] = u.z; cvs[c][d0 + 3] = u.w;
  }
  if (tid < 64) {
    int r = tid >> 4, d0 = (tid & 15) * 4;
    float4 t = *(const float4*)(qg + (size_t)(i0 + r) * DIMM + h * HD + d0);
    qs[r][d0] = t.x; qs[r][d0 + 1] = t.y; qs[r][d0 + 2] = t.z; qs[r][d0 + 3] = t.w;
  } else if (tid < 128) {
    kms[tid - 64] = k_mem[h * HD + tid - 64];
  } else if (tid < 192) {
    vms[tid - 128] = v_mem[h * HD + tid - 128];
  }
  __syncthreads();

  const ushort* kbase = khm_h + (size_t)h * 65536;
  const ushort* vbase = vhm_h + (size_t)h * 65536;

  int qi = i0 + w;   // one row per wave
  {
    // ===== compressed attention (split chains) =====
    float d0a = 0.f, d1a = 0.f, d2a = 0.f, d3a = 0.f;
    float m0a = 0.f, m1a = 0.f, m2a = 0.f, m3a = 0.f;
#pragma unroll
    for (int e = 0; e < 64; e += 4) {
      d0a = fmaf(qs[w][e],     ckt[e][lane],     d0a);
      d1a = fmaf(qs[w][e + 1], ckt[e + 1][lane], d1a);
      d2a = fmaf(qs[w][e + 2], ckt[e + 2][lane], d2a);
      d3a = fmaf(qs[w][e + 3], ckt[e + 3][lane], d3a);
      m0a = fmaf(qs[w][e],     kms[e],     m0a);
      m1a = fmaf(qs[w][e + 1], kms[e + 1], m1a);
      m2a = fmaf(qs[w][e + 2], kms[e + 2], m2a);
      m3a = fmaf(qs[w][e + 3], kms[e + 3], m3a);
    }
    float dot = (d0a + d1a) + (d2a + d3a);
    float dm  = (m0a + m1a) + (m2a + m3a);
    bool vis = (lane * BCB + BCB - 1) < qi;
    float sj = vis ? dot * SCALE : NEGV;
    float smem = dm * SCALE;
    float m = wred_max(fmaxf(sj, smem));
    float p = expf(sj - m);
    float pmem = expf(smem - m);
    float l = wred_sum(p) + pmem;
    float inv = 1.f / l;

    // ===== rank-based top-8: order = (value desc, index asc), same as butterfly =====
    float impv = vis ? p : NEGV;
    ivs[w][lane] = impv;
    sp[w][lane] = p;
    // wave-internal LDS write->read; lockstep wave64, compiler inserts lgkmcnt
    int r0 = 0, r1 = 0, r2 = 0, r3 = 0;
#pragma unroll
    for (int j = 0; j < 64; j += 4) {
      float v0 = ivs[w][j],     v1 = ivs[w][j + 1];
      float v2 = ivs[w][j + 2], v3 = ivs[w][j + 3];
      r0 += (v0 > impv || (v0 == impv && (j)     < lane)) ? 1 : 0;
      r1 += (v1 > impv || (v1 == impv && (j + 1) < lane)) ? 1 : 0;
      r2 += (v2 > impv || (v2 == impv && (j + 2) < lane)) ? 1 : 0;
      r3 += (v3 > impv || (v3 == impv && (j + 3) < lane)) ? 1 : 0;
    }
    int rank = (r0 + r1) + (r2 + r3);
    if (rank < KSEL) sels[w][rank] = (impv >= 0.f) ? lane : -1;

    float o0 = pmem * vms[lane], o1 = 0.f, o2 = 0.f, o3 = 0.f;
#pragma unroll
    for (int j = 0; j < 64; j += 4) {
      o0 = fmaf(sp[w][j],     cvs[j][lane],     o0);
      o1 = fmaf(sp[w][j + 1], cvs[j + 1][lane], o1);
      o2 = fmaf(sp[w][j + 2], cvs[j + 2][lane], o2);
      o3 = fmaf(sp[w][j + 3], cvs[j + 3][lane], o3);
    }
    float od = (o0 + o1) + (o2 + o3);
    cout[(size_t)qi * DIMM + h * HD + lane] = od * inv;

    // ===== fine attention for row qi (sel read from per-wave LDS) =====
    int own = qi >> 4;
    float slv[3];
#pragma unroll
    for (int t = 0; t < 3; t++) {
      int key = t * 64 + lane;
      float sv = NEGV;
      if (key < 144) {
        int kk = key >> 4, krow = key & 15;
        int bidx; bool fvis;
        if (kk < KSEL) {
          bidx = sels[w][kk];
          fvis = (bidx >= 0);
          if (!fvis) bidx = 0;
        } else {
          bidx = own;
          fvis = (krow <= (qi & 15));
        }
        const ushort* kr = kbase + (size_t)(bidx * BSB + krow) * 64;
        float f0 = 0.f, f1 = 0.f, f2 = 0.f, f3 = 0.f;
#pragma unroll
        for (int e8 = 0; e8 < 8; e8++) {
          ushort kv8[8];
          *(int4*)kv8 = *(const int4*)(kr + e8 * 8);
          f0 = fmaf(qs[w][e8 * 8 + 0], b2f(kv8[0]), f0);
          f1 = fmaf(qs[w][e8 * 8 + 1], b2f(kv8[1]), f1);
          f2 = fmaf(qs[w][e8 * 8 + 2], b2f(kv8[2]), f2);
          f3 = fmaf(qs[w][e8 * 8 + 3], b2f(kv8[3]), f3);
          f0 = fmaf(qs[w][e8 * 8 + 4], b2f(kv8[4]), f0);
          f1 = fmaf(qs[w][e8 * 8 + 5], b2f(kv8[5]), f1);
          f2 = fmaf(qs[w][e8 * 8 + 6], b2f(kv8[6]), f2);
          f3 = fmaf(qs[w][e8 * 8 + 7], b2f(kv8[7]), f3);
        }
        float fd = (f0 + f1) + (f2 + f3);
        sv = fvis ? fd * SCALE : NEGV;
      }
      slv[t] = sv;
    }
    float fm = wred_max(fmaxf(fmaxf(slv[0], slv[1]), slv[2]));
    float fsum = 0.f;
#pragma unroll
    for (int t = 0; t < 3; t++) {
      int key = t * 64 + lane;
      if (key < 144) {
        float pv = expf(slv[t] - fm);
        spf[w][key] = pv;
        fsum += pv;
      }
    }
    fsum = wred_sum(fsum);
    float finv = 1.f / fsum;

    float a0 = 0.f, a1 = 0.f, a2 = 0.f, a3 = 0.f;
#pragma unroll
    for (int kk = 0; kk < KSEL + 1; kk++) {
      int bidx = (kk < KSEL) ? sels[w][kk] : own;
      if (bidx < 0) bidx = 0;
      const ushort* vr = vbase + (size_t)(bidx * BSB) * 64 + lane;
#pragma unroll
      for (int krow = 0; krow < 16; krow += 4) {
        a0 = fmaf(spf[w][kk * 16 + krow],     b2f(vr[(size_t)(krow) * 64]),     a0);
        a1 = fmaf(spf[w][kk * 16 + krow + 1], b2f(vr[(size_t)(krow + 1) * 64]), a1);
        a2 = fmaf(spf[w][kk * 16 + krow + 2], b2f(vr[(size_t)(krow + 2) * 64]), a2);
        a3 = fmaf(spf[w][kk * 16 + krow + 3], b2f(vr[(size_t)(krow + 3) * 64]), a3);
      }
    }
    float facc = (a0 + a1) + (a2 + a3);
    fout[(size_t)qi * DIMM + h * HD + lane] = facc * finv;
  }
}

extern "C" void kernel_launch(void* const* d_in, const int* in_sizes, int n_in,
                              void* d_out, int out_size, void* d_ws, size_t ws_size,
                              hipStream_t stream) {
  const float* x     = (const float*)d_in[0];
  const float* ve    = (const float*)d_in[1]; (void)ve;
  const float* x0    = (const float*)d_in[2];
  const float* lam   = (const float*)d_in[3];
  const float* Wq    = (const float*)d_in[4];
  const float* Wk    = (const float*)d_in[5];
  const float* Wv    = (const float*)d_in[6];
  const float* Wo    = (const float*)d_in[7];
  const float* Wg    = (const float*)d_in[8];
  const float* k_pos = (const float*)d_in[9];
  const float* v_pos = (const float*)d_in[10];
  const float* Wck   = (const float*)d_in[11];
  const float* bck   = (const float*)d_in[12];
  const float* Wcv   = (const float*)d_in[13];
  const float* bcv   = (const float*)d_in[14];
  const float* k_mem = (const float*)d_in[15];
  const float* v_mem = (const float*)d_in[16];
  const float* W1    = (const float*)d_in[17];
  const float* W2    = (const float*)d_in[18];
  float* out = (float*)d_out;
  float* ws  = (float*)d_ws;

  const size_t NW = (size_t)NTOK * DIMM;   // 524288
  float* xr    = ws;              // f32 residual (read by rms_bf)
  float* xn    = ws + 1 * NW;     // xnh/xnl bf16 planes (dead after qkv)
  float* q     = ws + 2 * NW;     // q f32; later Wo partial p1w, then h1b (lower)
  float* kslot = ws + 3 * NW;     // khm_h/khm_l bf16; later p0w, then h1b (upper)
  float* vslot = ws + 4 * NW;     // vhm_h/vhm_l bf16
  float* coutb = ws + 5 * NW;
  float* foutb = ws + 6 * NW;
  float* soutb = ws + 7 * NW;     // later: ybf (bf16 overlay)
  float* gates = ws + 9 * NW;
  float* ckb   = gates + 32768;
  float* cvb   = ckb + 32768;
  ushort* qkvTh = (ushort*)(cvb + 32768 + 65536);
  ushort* qkvTl = qkvTh + 1600 * 512;
  ushort* WoT   = qkvTl + 1600 * 512;
  ushort* W1T   = WoT   + 512 * 512;
  ushort* W2T   = W1T   + 2048 * 512;
  ushort* WckTh = W2T   + 512 * 2048;
  ushort* WckTl = WckTh + 64 * 1024;
  ushort* WcvTh = WckTl + 64 * 1024;
  ushort* WcvTl = WcvTh + 64 * 1024;
  float* ctab   = (float*)(WcvTl + 64 * 1024);  // 1024 x 32
  float* stab   = ctab + 32768;
  float* pwk    = stab + 32768;                 // 8 x 64 (pos@Wck + bck)
  float* pwv    = pwk + 512;

  ushort* xnh = (ushort*)xn;          // bf16 hi plane of rms(x)
  ushort* xnl = xnh + NW;             // bf16 lo plane
  ushort* khm_h = (ushort*)kslot;     // rope'd k, head-major, bf16 hi
  ushort* khm_l = khm_h + 524288;     // lo
  ushort* vhm_h = (ushort*)vslot;     // v head-major bf16 hi
  ushort* vhm_l = vhm_h + 524288;     // lo
  float* p0w = kslot;                 // Wo split-K partials (k/v mirrors dead after cmpf)
  float* p1w = q;
  ushort* ybf = (ushort*)soutb;       // bf16 y (soutb dead after wo)
  ushort* h1b = (ushort*)q;           // bf16 h1 (slots 2-3, after rms_bf read p's)

  WtrPack pk;
  pk.d[0] = {Wq, qkvTh,              qkvTl,              512, 512,  512};
  pk.d[1] = {Wk, qkvTh + 512 * 512,  qkvTl + 512 * 512,  512, 512,  512};
  pk.d[2] = {Wv, qkvTh + 1024 * 512, qkvTl + 1024 * 512, 512, 512,  512};
  pk.d[3] = {Wo, WoT, nullptr,  512, 512,  512};
  pk.d[4] = {W1, W1T, nullptr,  512, 2048, 2048};
  pk.d[5] = {W2, W2T, nullptr, 2048, 512,  512};
  pk.d[6] = {Wck, WckTh, WckTl, 1024, 64, 64};
  pk.d[7] = {Wcv, WcvTh, WcvTl, 1024, 64, 64};
  pk.d[8] = {Wg, qkvTh + 1536 * 512, qkvTl + 1536 * 512, 512, 24, 64};
  int cum = 0;
  for (int e = 0; e < 9; e++) {
    cum += (pk.d[e].Npad / 32) * (pk.d[e].K / 32);
    pk.cum[e] = cum;
  }

  // roots: transposes + resid/rms + trig tables + pos@W, one launch
  k_pre<<<cum + NTOK + 128 + 16, 256, 0, stream>>>(
      pk, x, x0, lam, xr, xnh, xnl, ctab, stab,
      k_pos, v_pos, Wck, Wcv, bck, bcv, pwk, pwv);

  // QKV GEMM 128x64 tiles with fused RoPE + bf16 hi/lo k/v mirrors
  k_gemm_qkv<<<dim3(25, NTOK / 128), 256, 0, stream>>>(
      xnh, xnl, qkvTh, qkvTl, q, khm_h, khm_l, vhm_h, vhm_l, gates,
      ctab, stab);

  // merged: ckcv (32 blocks) || swin (128 blocks)
  k_mid<<<160, 256, 0, stream>>>(khm_h, khm_l, vhm_h, vhm_l,
                                 WckTh, WckTl, WcvTh, WcvTl,
                                 pwk, pwv, ckb, cvb, q, soutb);

  // fused cmp + top-8(rank) + fine; 4 rows/block, 1 row/wave -> 2048 blocks
  k_cmpf<<<dim3(NTOK / 4, NH), 256, 0, stream>>>(
      q, ckb, cvb, k_mem, v_mem, khm_h, vhm_h, coutb, foutb);

  // Wo split-K=2; combine folded into rms_bf
  k_gemm_wo<<<dim3(512 / 64, NTOK / 64, 2), 256, 0, stream>>>(
      coutb, foutb, soutb, gates, WoT, p0w, p1w);
  // rms_bf pre-fills out with x2; W2 atomically accumulates on top
  k_rms_bf<<<NTOK, 256, 0, stream>>>(xr, p0w, p1w, out, ybf);

  // W1: 64x64 tiles -> 512 blocks (2/CU; was 256 = 1/CU grid-bound)
  k_gemm_w1<<<dim3(2048 / 64, NTOK / 64), 256, 0, stream>>>(ybf, W1T, h1b);
  // W2: split-K=4 -> 512 blocks (2/CU; was 256 = 1/CU grid-bound)
  k_gemm_w2<<<dim3(512 / 64, NTOK / 64, 4), 256, 0, stream>>>(h1b, W2T, out);
}

// Round 18
// 227.263 us; speedup vs baseline: 1.0125x; 1.0125x over previous
//
#include <hip/hip_runtime.h>
#include <math.h>

#define NTOK 1024
#define DIMM 512
#define NH 8
#define HD 64
#define BCB 16
#define BSB 16
#define KSEL 8
#define WWIN 256
#define CBLK 64
#define SCALE 0.125f
#define EPSV 1e-6f
#define NEGV -1e30f

typedef short bf16x8 __attribute__((ext_vector_type(8)));
typedef float f32x4 __attribute__((ext_vector_type(4)));

__device__ inline ushort f2b(float f) {
  union { float f; unsigned int u; } c; c.f = f;
  unsigned int u = c.u;
  return (ushort)((u + 0x7FFFu + ((u >> 16) & 1u)) >> 16);
}
__device__ inline float b2f(ushort h) {
  union { unsigned int u; float f; } c; c.u = ((unsigned int)h) << 16;
  return c.f;
}

__device__ inline float wred_max(float v) {
#pragma unroll
  for (int off = 1; off < 64; off <<= 1) v = fmaxf(v, __shfl_xor(v, off));
  return v;
}
__device__ inline float wred_sum(float v) {
#pragma unroll
  for (int off = 1; off < 64; off <<= 1) v += __shfl_xor(v, off);
  return v;
}

// ---------- roots: weight transposes + resid/rms + trig tables + pos@W ----------
struct WtrDesc { const float* src; ushort* dh; ushort* dl; int K; int Nsrc; int Npad; };
struct WtrPack { WtrDesc d[9]; int cum[9]; };

__global__ void __launch_bounds__(256)
k_pre(WtrPack pk, const float* __restrict__ x, const float* __restrict__ x0,
      const float* __restrict__ lam, float* __restrict__ xr,
      ushort* __restrict__ xnh, ushort* __restrict__ xnl,
      float* __restrict__ ctab, float* __restrict__ stab,
      const float* __restrict__ k_pos, const float* __restrict__ v_pos,
      const float* __restrict__ Wck, const float* __restrict__ Wcv,
      const float* __restrict__ bck, const float* __restrict__ bcv,
      float* __restrict__ pwk, float* __restrict__ pwv) {
  __shared__ float t[32][33];
  __shared__ float sm[8];
  __shared__ float red[4][64];
  int bid = blockIdx.x, tid = threadIdx.x;
  if (bid < pk.cum[8]) {
    // ---- weight transpose (f32 K x N -> bf16 hi/lo N x K) ----
    int gb = bid;
    int e = 0;
    while (gb >= pk.cum[e]) e++;
    int start = e ? pk.cum[e - 1] : 0;
    WtrDesc dd = pk.d[e];
    int local = gb - start;
    int XT = dd.Npad >> 5;
    int bx = local % XT, by = local / XT;
    int n0 = bx * 32, k0 = by * 32;
    int tx = tid & 31, ty = tid >> 5;
#pragma unroll
    for (int i = 0; i < 32; i += 8)
      t[ty + i][tx] = (n0 + tx < dd.Nsrc)
          ? dd.src[(size_t)(k0 + ty + i) * dd.Nsrc + n0 + tx] : 0.f;
    __syncthreads();
#pragma unroll
    for (int i = 0; i < 32; i += 8) {
      float vv = t[tx][ty + i];
      ushort h = f2b(vv);
      size_t di = (size_t)(n0 + ty + i) * dd.K + k0 + tx;
      dd.dh[di] = h;
      if (dd.dl) dd.dl[di] = f2b(vv - b2f(h));
    }
  } else if (bid < pk.cum[8] + NTOK) {
    // ---- residual mix + rmsnorm, bf16 hi/lo out ----
    int row = bid - pk.cum[8];
    float l0 = lam[0], l1 = lam[1];
    size_t b = (size_t)row * DIMM;
    float a0 = l0 * x[b + tid]       + l1 * x0[b + tid];
    float a1 = l0 * x[b + tid + 256] + l1 * x0[b + tid + 256];
    xr[b + tid] = a0; xr[b + tid + 256] = a1;
    float ss = a0 * a0 + a1 * a1;
    for (int o = 32; o > 0; o >>= 1) ss += __shfl_down(ss, o);
    int lane = tid & 63, wid = tid >> 6;
    if (lane == 0) sm[wid] = ss;
    __syncthreads();
    if (tid == 0) {
      float s = sm[0] + sm[1] + sm[2] + sm[3];
      sm[0] = rsqrtf(s / (float)DIMM + EPSV);
    }
    __syncthreads();
    float r = sm[0];
    float v0 = a0 * r, v1 = a1 * r;
    ushort h0 = f2b(v0), h1 = f2b(v1);
    xnh[b + tid] = h0;        xnh[b + tid + 256] = h1;
    xnl[b + tid] = f2b(v0 - b2f(h0));
    xnl[b + tid + 256] = f2b(v1 - b2f(h1));
  } else if (bid < pk.cum[8] + NTOK + 128) {
    // ---- RoPE cos/sin tables: [n][d<32] ----
    int g = (bid - pk.cum[8] - NTOK) * 256 + tid;
    int n = g >> 5, d = g & 31;
    float inv = powf(10000.f, -(float)d / 32.f);
    float sn, cs;
    sincosf((float)n * inv, &sn, &cs);
    ctab[g] = cs; stab[g] = sn;
  } else {
    // ---- pw[h][d] = pos[h]@W + bias (16 blocks: (kv,h)) ----
    int idx2 = bid - pk.cum[8] - NTOK - 128;
    int h = idx2 & 7, kv = idx2 >> 3;
    const float* pos = kv ? v_pos : k_pos;
    const float* W = kv ? Wcv : Wck;
    const float* bias = kv ? bcv : bck;
    float* pw = kv ? pwv : pwk;
    int d = tid & 63, part = tid >> 6;
    float s = 0.f;
    for (int i = 0; i < 256; i++) {
      int kk = part * 256 + i;
      s += pos[h * 1024 + kk] * W[(size_t)kk * 64 + d];
    }
    red[part][d] = s;
    __syncthreads();
    if (part == 0)
      pw[h * 64 + d] = red[0][d] + red[1][d] + red[2][d] + red[3][d] + bias[d];
  }
}

// ---------- fused Wo-combine + rmsnorm: out = xr+p0+p1 ; y = bf16(rms(out)) ----------
__global__ void __launch_bounds__(256)
k_rms_bf(const float* __restrict__ xr, const float* __restrict__ p0,
         const float* __restrict__ p1, float* __restrict__ outb,
         ushort* __restrict__ y) {
  int row = blockIdx.x, tid = threadIdx.x;
  size_t b = (size_t)row * DIMM;
  float a0 = xr[b + tid]       + p0[b + tid]       + p1[b + tid];
  float a1 = xr[b + tid + 256] + p0[b + tid + 256] + p1[b + tid + 256];
  outb[b + tid] = a0; outb[b + tid + 256] = a1;
  float ss = a0 * a0 + a1 * a1;
  __shared__ float sm[8];
  for (int o = 32; o > 0; o >>= 1) ss += __shfl_down(ss, o);
  int lane = tid & 63, wid = tid >> 6;
  if (lane == 0) sm[wid] = ss;
  __syncthreads();
  if (tid == 0) {
    float s = sm[0] + sm[1] + sm[2] + sm[3];
    sm[0] = rsqrtf(s / (float)DIMM + EPSV);
  }
  __syncthreads();
  float r = sm[0];
  y[b + tid] = f2b(a0 * r); y[b + tid + 256] = f2b(a1 * r);
}

// ---------- W1 GEMM: 128Mx64N tile, A bf16, relu^2 -> bf16. grid (32,8) ----------
__global__ void __launch_bounds__(256)
k_gemm_w1(const ushort* __restrict__ A, const ushort* __restrict__ BT,
          ushort* __restrict__ Co) {
  const int Kd = 512, Nd = 2048;
  __shared__ ushort As[128 * 40];
  __shared__ ushort Bs[64 * 40];
  int tid = threadIdx.x;
  int lane = tid & 63, w = tid >> 6;
  int rb = blockIdx.y * 128, cb = blockIdx.x * 64;
  int wm = (w >> 1) * 64, wn = (w & 1) * 32;
  int quad = lane >> 4, l15 = lane & 15;
  int srA = tid >> 1, scA = (tid & 1) * 16;
  int srB = tid >> 2, scB = (tid & 3) * 8;

  f32x4 acc[4][2];
#pragma unroll
  for (int i = 0; i < 4; i++)
#pragma unroll
    for (int j = 0; j < 2; j++) acc[i][j] = (f32x4){0.f, 0.f, 0.f, 0.f};

  const ushort* ap = A  + (size_t)(rb + srA) * Kd + scA;
  const ushort* bp = BT + (size_t)(cb + srB) * Kd + scB;
  ushort* aw = &As[srA * 40 + scA];
  ushort* bw = &Bs[srB * 40 + scB];

  int4 pa0 = *(const int4*)ap;
  int4 pa1 = *(const int4*)(ap + 8);
  int4 pb  = *(const int4*)bp;

  for (int k0 = 0; k0 < Kd; k0 += 32) {
    if (k0) __syncthreads();
    *(int4*)aw = pa0; *(int4*)(aw + 8) = pa1;
    *(int4*)bw = pb;
    __syncthreads();
    if (k0 + 32 < Kd) {
      pa0 = *(const int4*)(ap + k0 + 32);
      pa1 = *(const int4*)(ap + k0 + 40);
      pb  = *(const int4*)(bp + k0 + 32);
    }
    bf16x8 af[4], bfr[2];
#pragma unroll
    for (int t = 0; t < 4; t++)
      af[t] = *(const bf16x8*)&As[(wm + t * 16 + l15) * 40 + quad * 8];
#pragma unroll
    for (int t = 0; t < 2; t++)
      bfr[t] = *(const bf16x8*)&Bs[(wn + t * 16 + l15) * 40 + quad * 8];
#pragma unroll
    for (int i = 0; i < 4; i++)
#pragma unroll
      for (int j = 0; j < 2; j++)
        acc[i][j] = __builtin_amdgcn_mfma_f32_16x16x32_bf16(af[i], bfr[j],
                                                            acc[i][j], 0, 0, 0);
  }

#pragma unroll
  for (int i = 0; i < 4; i++) {
#pragma unroll
    for (int j = 0; j < 2; j++) {
      int col = cb + wn + j * 16 + l15;
#pragma unroll
      for (int r = 0; r < 4; r++) {
        int row = rb + wm + i * 16 + quad * 4 + r;
        float t = fmaxf(acc[i][j][r], 0.f);
        Co[(size_t)row * Nd + col] = f2b(t * t);
      }
    }
  }
}

// ---------- W2 GEMM: 64x64 tile, split-K=2, atomicAdd into out (pre-filled with x2) ----------
__global__ void __launch_bounds__(256)
k_gemm_w2(const ushort* __restrict__ A, const ushort* __restrict__ BT,
          float* __restrict__ outb) {
  const int Kd = 2048;
  __shared__ ushort As[64 * 40];
  __shared__ ushort Bs[64 * 40];
  int tid = threadIdx.x;
  int lane = tid & 63, w = tid >> 6;
  int rb = blockIdx.y * 64, cb = blockIdx.x * 64;
  int kb = blockIdx.z * 1024;
  int wm = (w >> 1) * 32, wn = (w & 1) * 32;
  int quad = lane >> 4, l15 = lane & 15;
  int srow = tid >> 2, scol = (tid & 3) * 8;

  f32x4 acc[2][2];
#pragma unroll
  for (int i = 0; i < 2; i++)
#pragma unroll
    for (int j = 0; j < 2; j++) acc[i][j] = (f32x4){0.f, 0.f, 0.f, 0.f};

  const ushort* ap = A  + (size_t)(rb + srow) * Kd + kb + scol;
  const ushort* bp = BT + (size_t)(cb + srow) * Kd + kb + scol;
  ushort* aw = &As[srow * 40 + scol];
  ushort* bw = &Bs[srow * 40 + scol];

  int4 pa = *(const int4*)ap;
  int4 pb = *(const int4*)bp;

  for (int k0 = 0; k0 < 1024; k0 += 32) {
    if (k0) __syncthreads();
    *(int4*)aw = pa;
    *(int4*)bw = pb;
    __syncthreads();
    if (k0 + 32 < 1024) {
      pa = *(const int4*)(ap + k0 + 32);
      pb = *(const int4*)(bp + k0 + 32);
    }
    bf16x8 af[2], bfr[2];
#pragma unroll
    for (int t = 0; t < 2; t++) {
      af[t]  = *(const bf16x8*)&As[(wm + t * 16 + l15) * 40 + quad * 8];
      bfr[t] = *(const bf16x8*)&Bs[(wn + t * 16 + l15) * 40 + quad * 8];
    }
#pragma unroll
    for (int i = 0; i < 2; i++)
#pragma unroll
      for (int j = 0; j < 2; j++)
        acc[i][j] = __builtin_amdgcn_mfma_f32_16x16x32_bf16(af[i], bfr[j],
                                                            acc[i][j], 0, 0, 0);
  }

#pragma unroll
  for (int i = 0; i < 2; i++) {
#pragma unroll
    for (int j = 0; j < 2; j++) {
      int col = cb + wn + j * 16 + l15;
#pragma unroll
      for (int r = 0; r < 4; r++) {
        int row = rb + wm + i * 16 + quad * 4 + r;
        atomicAdd(&outb[(size_t)row * 512 + col], acc[i][j][r]);
      }
    }
  }
}

// ---------- Wo GEMM, split-K=2, prefetched gated combine (loads overlap MFMA) ----------
__global__ void __launch_bounds__(256)
k_gemm_wo(const float* __restrict__ cg, const float* __restrict__ fg,
          const float* __restrict__ sg, const float* __restrict__ gates,
          const ushort* __restrict__ BT, float* __restrict__ P0,
          float* __restrict__ P1) {
  __shared__ ushort As[64 * 40];
  __shared__ ushort Bs[64 * 40];
  int tid = threadIdx.x;
  int lane = tid & 63, wave = tid >> 6;
  int rb = blockIdx.y * 64, cb = blockIdx.x * 64;
  int kb = blockIdx.z * 256;
  int wm = (wave >> 1) * 32, wn = (wave & 1) * 32;
  int q = lane >> 4, l15 = lane & 15;
  int srow = tid >> 2, scol = (tid & 3) * 8;

  f32x4 acc[2][2];
#pragma unroll
  for (int i = 0; i < 2; i++)
#pragma unroll
    for (int j = 0; j < 2; j++) acc[i][j] = (f32x4){0.f, 0.f, 0.f, 0.f};

  int row = rb + srow;
  const ushort* bp = BT + (size_t)(cb + srow) * 512 + kb + scol;
  ushort* aw = &As[srow * 40 + scol];
  ushort* bw = &Bs[srow * 40 + scol];

  // prefetch registers for the gated-combine A fragment + B fragment
  ushort hcur[8];
  int4 pbcur;
  {
    int colb = kb + scol;
    int hh = colb >> 6;
    const float* gp = gates + (size_t)row * 24 + hh * 3;
    float g0 = gp[0], g1 = gp[1], g2 = gp[2];
    size_t off = (size_t)row * 512 + colb;
    float4 c0 = *(const float4*)(cg + off), c1 = *(const float4*)(cg + off + 4);
    float4 f0 = *(const float4*)(fg + off), f1 = *(const float4*)(fg + off + 4);
    float4 s0 = *(const float4*)(sg + off), s1 = *(const float4*)(sg + off + 4);
    hcur[0] = f2b(g0 * c0.x + g1 * f0.x + g2 * s0.x);
    hcur[1] = f2b(g0 * c0.y + g1 * f0.y + g2 * s0.y);
    hcur[2] = f2b(g0 * c0.z + g1 * f0.z + g2 * s0.z);
    hcur[3] = f2b(g0 * c0.w + g1 * f0.w + g2 * s0.w);
    hcur[4] = f2b(g0 * c1.x + g1 * f1.x + g2 * s1.x);
    hcur[5] = f2b(g0 * c1.y + g1 * f1.y + g2 * s1.y);
    hcur[6] = f2b(g0 * c1.z + g1 * f1.z + g2 * s1.z);
    hcur[7] = f2b(g0 * c1.w + g1 * f1.w + g2 * s1.w);
    pbcur = *(const int4*)bp;
  }

  for (int k0 = 0; k0 < 256; k0 += 32) {
    if (k0) __syncthreads();
    *(int4*)aw = *(int4*)hcur;
    *(int4*)bw = pbcur;
    __syncthreads();
    if (k0 + 32 < 256) {
      int colb = kb + k0 + 32 + scol;
      int hh = colb >> 6;
      const float* gp = gates + (size_t)row * 24 + hh * 3;
      float g0 = gp[0], g1 = gp[1], g2 = gp[2];
      size_t off = (size_t)row * 512 + colb;
      float4 c0 = *(const float4*)(cg + off), c1 = *(const float4*)(cg + off + 4);
      float4 f0 = *(const float4*)(fg + off), f1 = *(const float4*)(fg + off + 4);
      float4 s0 = *(const float4*)(sg + off), s1 = *(const float4*)(sg + off + 4);
      hcur[0] = f2b(g0 * c0.x + g1 * f0.x + g2 * s0.x);
      hcur[1] = f2b(g0 * c0.y + g1 * f0.y + g2 * s0.y);
      hcur[2] = f2b(g0 * c0.z + g1 * f0.z + g2 * s0.z);
      hcur[3] = f2b(g0 * c0.w + g1 * f0.w + g2 * s0.w);
      hcur[4] = f2b(g0 * c1.x + g1 * f1.x + g2 * s1.x);
      hcur[5] = f2b(g0 * c1.y + g1 * f1.y + g2 * s1.y);
      hcur[6] = f2b(g0 * c1.z + g1 * f1.z + g2 * s1.z);
      hcur[7] = f2b(g0 * c1.w + g1 * f1.w + g2 * s1.w);
      pbcur = *(const int4*)(bp + k0 + 32);
    }
    bf16x8 af[2], bfr[2];
#pragma unroll
    for (int t = 0; t < 2; t++) {
      af[t]  = *(const bf16x8*)&As[(wm + t * 16 + l15) * 40 + q * 8];
      bfr[t] = *(const bf16x8*)&Bs[(wn + t * 16 + l15) * 40 + q * 8];
    }
#pragma unroll
    for (int i = 0; i < 2; i++)
#pragma unroll
      for (int j = 0; j < 2; j++)
        acc[i][j] = __builtin_amdgcn_mfma_f32_16x16x32_bf16(af[i], bfr[j],
                                                            acc[i][j], 0, 0, 0);
  }

  float* pbuf = blockIdx.z ? P1 : P0;
#pragma unroll
  for (int i = 0; i < 2; i++) {
#pragma unroll
    for (int j = 0; j < 2; j++) {
      int col = cb + wn + j * 16 + l15;
#pragma unroll
      for (int r = 0; r < 4; r++) {
        int rr = rb + wm + i * 16 + q * 4 + r;
        pbuf[(size_t)rr * 512 + col] = acc[i][j][r];
      }
    }
  }
}

// ---------- QKV GEMM 128Mx64N with fused RoPE + bf16 hi/lo k/v mirrors + gates ----------
__global__ void __launch_bounds__(256)
k_gemm_qkv(const ushort* __restrict__ Ah, const ushort* __restrict__ Al,
           const ushort* __restrict__ BTh, const ushort* __restrict__ BTl,
           float* __restrict__ qout, ushort* __restrict__ khm_h,
           ushort* __restrict__ khm_l, ushort* __restrict__ vhm_h,
           ushort* __restrict__ vhm_l, float* __restrict__ gates,
           const float* __restrict__ ctab, const float* __restrict__ stab) {
  const int Kd = 512;
  __shared__ ushort SM[15360];   // Ash 128x40 | Asl 128x40 | Bsh 64x40 | Bsl 64x40
  ushort* Ash = SM;
  ushort* Asl = SM + 5120;
  ushort* Bsh = SM + 10240;
  ushort* Bsl = SM + 12800;
  int tid = threadIdx.x;
  int lane = tid & 63, wave = tid >> 6;
  int rb = blockIdx.y * 128, cb = blockIdx.x * 64;
  const bool prec = (cb < 1024);   // q/k columns need f32-grade (selection)
  int wm = (wave >> 1) * 64, wn = (wave & 1) * 32;
  int q = lane >> 4, l15 = lane & 15;
  int srA = tid >> 1, scA = (tid & 1) * 16;
  int srB = tid >> 2, scB = (tid & 3) * 8;

  f32x4 acc[4][2];
#pragma unroll
  for (int i = 0; i < 4; i++)
#pragma unroll
    for (int j = 0; j < 2; j++) acc[i][j] = (f32x4){0.f, 0.f, 0.f, 0.f};

  const ushort* aph = Ah  + (size_t)(rb + srA) * Kd + scA;
  const ushort* apl = Al  + (size_t)(rb + srA) * Kd + scA;
  const ushort* bph = BTh + (size_t)(cb + srB) * Kd + scB;
  const ushort* bpl = BTl + (size_t)(cb + srB) * Kd + scB;
  ushort* awh = &Ash[srA * 40 + scA];
  ushort* awl = &Asl[srA * 40 + scA];
  ushort* bwh = &Bsh[srB * 40 + scB];
  ushort* bwl = &Bsl[srB * 40 + scB];

  int4 ph0 = *(const int4*)aph;
  int4 ph1 = *(const int4*)(aph + 8);
  int4 pbh = *(const int4*)bph;
  int4 pl0, pl1, pbl;
  if (prec) {
    pl0 = *(const int4*)apl;
    pl1 = *(const int4*)(apl + 8);
    pbl = *(const int4*)bpl;
  }

  for (int k0 = 0; k0 < Kd; k0 += 32) {
    if (k0) __syncthreads();
    *(int4*)awh = ph0; *(int4*)(awh + 8) = ph1;
    *(int4*)bwh = pbh;
    if (prec) {
      *(int4*)awl = pl0; *(int4*)(awl + 8) = pl1;
      *(int4*)bwl = pbl;
    }
    __syncthreads();
    if (k0 + 32 < Kd) {
      ph0 = *(const int4*)(aph + k0 + 32);
      ph1 = *(const int4*)(aph + k0 + 40);
      pbh = *(const int4*)(bph + k0 + 32);
      if (prec) {
        pl0 = *(const int4*)(apl + k0 + 32);
        pl1 = *(const int4*)(apl + k0 + 40);
        pbl = *(const int4*)(bpl + k0 + 32);
      }
    }
    bf16x8 afh[4], bfh[2], afl[4], bfl[2];
#pragma unroll
    for (int t = 0; t < 4; t++)
      afh[t] = *(const bf16x8*)&Ash[(wm + t * 16 + l15) * 40 + q * 8];
#pragma unroll
    for (int t = 0; t < 2; t++)
      bfh[t] = *(const bf16x8*)&Bsh[(wn + t * 16 + l15) * 40 + q * 8];
    if (prec) {
#pragma unroll
      for (int t = 0; t < 4; t++)
        afl[t] = *(const bf16x8*)&Asl[(wm + t * 16 + l15) * 40 + q * 8];
#pragma unroll
      for (int t = 0; t < 2; t++)
        bfl[t] = *(const bf16x8*)&Bsl[(wn + t * 16 + l15) * 40 + q * 8];
    }
#pragma unroll
    for (int i = 0; i < 4; i++)
#pragma unroll
      for (int j = 0; j < 2; j++) {
        acc[i][j] = __builtin_amdgcn_mfma_f32_16x16x32_bf16(afh[i], bfh[j],
                                                            acc[i][j], 0, 0, 0);
        if (prec) {
          acc[i][j] = __builtin_amdgcn_mfma_f32_16x16x32_bf16(afh[i], bfl[j],
                                                              acc[i][j], 0, 0, 0);
          acc[i][j] = __builtin_amdgcn_mfma_f32_16x16x32_bf16(afl[i], bfh[j],
                                                              acc[i][j], 0, 0, 0);
        }
      }
  }

  if (prec) {
    // ---- fused RoPE epilogue: two 64-row half-passes via LDS overlay ----
    float* st = (float*)SM;   // 64 x 66 f32 = 16896 B (fits in 30720 B)
    int h = (cb & 511) >> 6;
#pragma unroll
    for (int hb = 0; hb < 2; hb++) {
      __syncthreads();
      if ((wave >> 1) == hb) {
#pragma unroll
        for (int i = 0; i < 4; i++)
#pragma unroll
          for (int j = 0; j < 2; j++)
#pragma unroll
            for (int r = 0; r < 4; r++)
              st[(i * 16 + q * 4 + r) * 66 + wn + j * 16 + l15] = acc[i][j][r];
      }
      __syncthreads();
#pragma unroll
      for (int e = 0; e < 8; e++) {
        int p = e * 256 + tid;          // 2048 pairs: 64 rows x 32 dims
        int rw = p >> 5, d = p & 31;
        int n = rb + hb * 64 + rw;
        float x1 = st[rw * 66 + d], x2 = st[rw * 66 + d + 32];
        float cs = ctab[n * 32 + d], sn = stab[n * 32 + d];
        float o1 = x1 * cs - x2 * sn;
        float o2 = x2 * cs + x1 * sn;
        if (cb < 512) {
          qout[(size_t)n * 512 + h * 64 + d]      = o1;
          qout[(size_t)n * 512 + h * 64 + d + 32] = o2;
        } else {
          size_t ob = (size_t)h * 65536 + (size_t)n * 64 + d;
          ushort b1 = f2b(o1), b2v = f2b(o2);
          khm_h[ob]      = b1;
          khm_h[ob + 32] = b2v;
          khm_l[ob]      = f2b(o1 - b2f(b1));
          khm_l[ob + 32] = f2b(o2 - b2f(b2v));
        }
      }
    }
  } else {
#pragma unroll
    for (int i = 0; i < 4; i++) {
#pragma unroll
      for (int j = 0; j < 2; j++) {
        int col = cb + wn + j * 16 + l15;
#pragma unroll
        for (int r = 0; r < 4; r++) {
          int row = rb + wm + i * 16 + q * 4 + r;
          float vv = acc[i][j][r];
          if (cb >= 1536) {
            int c24 = col - 1536;
            if (c24 < 24)
              gates[(size_t)row * 24 + c24] = 1.f / (1.f + expf(-vv));
          } else {
            int c = col - 1024;       // v plane -> head-major bf16 hi/lo
            size_t ob = (size_t)(c >> 6) * 65536 + (size_t)row * 64 + (c & 63);
            ushort hb = f2b(vv);
            vhm_h[ob] = hb;
            vhm_l[ob] = f2b(vv - b2f(hb));
          }
        }
      }
    }
  }
}

// ---------- merged: compressed k/v MFMA (blocks 0..31) || sliding-window flash (32..159) ----------
__global__ void __launch_bounds__(256)
k_mid(const ushort* __restrict__ khm_h, const ushort* __restrict__ khm_l,
      const ushort* __restrict__ vhm_h, const ushort* __restrict__ vhm_l,
      const ushort* __restrict__ WckTh, const ushort* __restrict__ WckTl,
      const ushort* __restrict__ WcvTh, const ushort* __restrict__ WcvTl,
      const float* __restrict__ pwk, const float* __restrict__ pwv,
      float* __restrict__ ckb, float* __restrict__ cvb,
      const float* __restrict__ qg, float* __restrict__ sout) {
  __shared__ union {
    struct { ushort Ash[32 * 72]; ushort Asl[32 * 72];
             ushort Bsh[64 * 72]; ushort Bsl[64 * 72]; } c;
    struct { ushort Kt[64 * 72]; ushort VT[64 * 72];
             ushort Qs[64 * 72]; ushort Ps[4][16 * 72]; } s;
  } U;
  int tid = threadIdx.x, lane = tid & 63, w = tid >> 6;
  int quad = lane >> 4, l15 = lane & 15;

  if (blockIdx.x < 32) {
    // ===== compressed k/v: pure int4 staging of pre-split hi/lo planes =====
    int h = blockIdx.x & 7, kv = (blockIdx.x >> 3) & 1, mh = blockIdx.x >> 4;
    const ushort* sH = kv ? vhm_h : khm_h;
    const ushort* sL = kv ? vhm_l : khm_l;
    const ushort* WTh = kv ? WcvTh : WckTh;
    const ushort* WTl = kv ? WcvTl : WckTl;
    const float* pw = (kv ? pwv : pwk) + h * 64;
    float* outp = kv ? cvb : ckb;

    ushort* Ash = U.c.Ash; ushort* Asl = U.c.Asl;
    ushort* Bsh = U.c.Bsh; ushort* Bsl = U.c.Bsl;
    int wmi = w >> 1, wnj = w & 1;
    int arow = tid >> 3, ae0 = (tid & 7) * 8;   // A: 32 rows x 64 cols
    int brow = tid >> 2, be0 = (tid & 3) * 16;  // B: 64 rows x 64 cols
    size_t abase = (size_t)h * 65536 + (size_t)(mh * 32 + arow) * 1024 + ae0;
    size_t bbase = (size_t)brow * 1024 + be0;

    f32x4 acc[2];
#pragma unroll
    for (int j = 0; j < 2; j++) acc[j] = (f32x4){0.f, 0.f, 0.f, 0.f};

    for (int t = 0; t < 16; t++) {
      int kb = t * 64;
      *(int4*)&Ash[arow * 72 + ae0] = *(const int4*)(sH + abase + kb);
      *(int4*)&Asl[arow * 72 + ae0] = *(const int4*)(sL + abase + kb);
      *(int4*)&Bsh[brow * 72 + be0]     = *(const int4*)(WTh + bbase + kb);
      *(int4*)&Bsh[brow * 72 + be0 + 8] = *(const int4*)(WTh + bbase + kb + 8);
      *(int4*)&Bsl[brow * 72 + be0]     = *(const int4*)(WTl + bbase + kb);
      *(int4*)&Bsl[brow * 72 + be0 + 8] = *(const int4*)(WTl + bbase + kb + 8);
      __syncthreads();
#pragma unroll
      for (int sub = 0; sub < 2; sub++) {
        int ar2 = (wmi * 16 + l15) * 72 + sub * 32 + quad * 8;
        bf16x8 afh = *(const bf16x8*)&Ash[ar2];
        bf16x8 afl = *(const bf16x8*)&Asl[ar2];
#pragma unroll
        for (int j = 0; j < 2; j++) {
          int br2 = (wnj * 32 + j * 16 + l15) * 72 + sub * 32 + quad * 8;
          bf16x8 bfh = *(const bf16x8*)&Bsh[br2];
          bf16x8 bfl = *(const bf16x8*)&Bsl[br2];
          acc[j] = __builtin_amdgcn_mfma_f32_16x16x32_bf16(afh, bfh, acc[j], 0, 0, 0);
          acc[j] = __builtin_amdgcn_mfma_f32_16x16x32_bf16(afh, bfl, acc[j], 0, 0, 0);
          acc[j] = __builtin_amdgcn_mfma_f32_16x16x32_bf16(afl, bfh, acc[j], 0, 0, 0);
        }
      }
      __syncthreads();
    }

#pragma unroll
    for (int j = 0; j < 2; j++) {
      int d = wnj * 32 + j * 16 + l15;
      float bv = pw[d];
#pragma unroll
      for (int r = 0; r < 4; r++) {
        int c = mh * 32 + wmi * 16 + quad * 4 + r;
        outp[((size_t)h * 64 + c) * 64 + d] = acc[j][r] + bv;
      }
    }
  } else {
    // ===== sliding window flash: 64 q-rows / 4 waves per block =====
    int sidx = blockIdx.x - 32;
    int h = sidx >> 4, i0 = (sidx & 15) * 64;
    ushort* Kt = U.s.Kt; ushort* VT = U.s.VT; ushort* Qs = U.s.Qs;

#pragma unroll
    for (int it = 0; it < 2; it++) {
      int f = it * 256 + tid;            // 512 chunks of 8 ushorts (64 rows)
      int r = f >> 3, d0 = (f & 7) * 8;
      const float* qp = qg + (size_t)(i0 + r) * DIMM + h * HD + d0;
      float4 t0 = *(const float4*)qp;
      float4 t1 = *(const float4*)(qp + 4);
      ushort u[8] = {f2b(t0.x), f2b(t0.y), f2b(t0.z), f2b(t0.w),
                     f2b(t1.x), f2b(t1.y), f2b(t1.z), f2b(t1.w)};
      *(int4*)&Qs[r * 72 + d0] = *(int4*)u;
    }

    int lo = i0 - (WWIN - 1); if (lo < 0) lo = 0;
    int jb_lo = lo >> 6, jb_hi = (i0 + 63) >> 6;

    float mrow[4], lrow[4];
    f32x4 Of[4];
#pragma unroll
    for (int r = 0; r < 4; r++) { mrow[r] = NEGV; lrow[r] = 0.f; }
#pragma unroll
    for (int d = 0; d < 4; d++) Of[d] = (f32x4){0.f, 0.f, 0.f, 0.f};

    for (int jb = jb_lo; jb <= jb_hi; jb++) {
      __syncthreads();
#pragma unroll
      for (int it = 0; it < 2; it++) {
        int f = it * 256 + tid;          // 512 chunks (64 rows)
        int r = f >> 3, c8 = (f & 7) * 8;
        const ushort* kp = khm_h + (size_t)h * 65536 + (size_t)(jb * 64 + r) * 64 + c8;
        *(int4*)&Kt[r * 72 + c8] = *(const int4*)kp;
        const ushort* vp = vhm_h + (size_t)h * 65536 + (size_t)(jb * 64 + r) * 64 + c8;
        ushort vv[8];
        *(int4*)vv = *(const int4*)vp;
#pragma unroll
        for (int e = 0; e < 8; e++) VT[(c8 + e) * 72 + r] = vv[e];
      }
      __syncthreads();

      bf16x8 qa[2];
#pragma unroll
      for (int c = 0; c < 2; c++)
        qa[c] = *(const bf16x8*)&Qs[(w * 16 + l15) * 72 + c * 32 + quad * 8];

      f32x4 sc[4];
      __builtin_amdgcn_s_setprio(1);
#pragma unroll
      for (int ks = 0; ks < 4; ks++) {
        f32x4 a = (f32x4){0.f, 0.f, 0.f, 0.f};
#pragma unroll
        for (int c = 0; c < 2; c++) {
          bf16x8 kb = *(const bf16x8*)&Kt[(ks * 16 + l15) * 72 + c * 32 + quad * 8];
          a = __builtin_amdgcn_mfma_f32_16x16x32_bf16(qa[c], kb, a, 0, 0, 0);
        }
        sc[ks] = a;
      }
      __builtin_amdgcn_s_setprio(0);

      float pm[4][4], rmax[4];
#pragma unroll
      for (int r = 0; r < 4; r++) rmax[r] = NEGV;
#pragma unroll
      for (int ks = 0; ks < 4; ks++) {
        int gj = jb * 64 + ks * 16 + l15;
#pragma unroll
        for (int r = 0; r < 4; r++) {
          int qi = i0 + w * 16 + quad * 4 + r;
          bool vis = (gj <= qi) && (qi - gj < WWIN);
          float s = vis ? sc[ks][r] * SCALE : NEGV;
          pm[ks][r] = s;
          rmax[r] = fmaxf(rmax[r], s);
        }
      }
#pragma unroll
      for (int off = 1; off < 16; off <<= 1)
#pragma unroll
        for (int r = 0; r < 4; r++)
          rmax[r] = fmaxf(rmax[r], __shfl_xor(rmax[r], off));

      float alpha[4], rsum[4];
#pragma unroll
      for (int r = 0; r < 4; r++) {
        float newm = fmaxf(mrow[r], rmax[r]);
        alpha[r] = expf(mrow[r] - newm);
        mrow[r] = newm;
        rsum[r] = 0.f;
      }
#pragma unroll
      for (int ks = 0; ks < 4; ks++)
#pragma unroll
        for (int r = 0; r < 4; r++) {
          float p = expf(pm[ks][r] - mrow[r]);
          pm[ks][r] = p;
          rsum[r] += p;
        }
#pragma unroll
      for (int off = 1; off < 16; off <<= 1)
#pragma unroll
        for (int r = 0; r < 4; r++)
          rsum[r] += __shfl_xor(rsum[r], off);
#pragma unroll
      for (int r = 0; r < 4; r++)
        lrow[r] = lrow[r] * alpha[r] + rsum[r];

#pragma unroll
      for (int ks = 0; ks < 4; ks++)
#pragma unroll
        for (int r = 0; r < 4; r++)
          U.s.Ps[w][(quad * 4 + r) * 72 + ks * 16 + l15] = f2b(pm[ks][r]);
#pragma unroll
      for (int d = 0; d < 4; d++)
#pragma unroll
        for (int r = 0; r < 4; r++)
          Of[d][r] *= alpha[r];

      __builtin_amdgcn_s_setprio(1);
#pragma unroll
      for (int c = 0; c < 2; c++) {
        bf16x8 pa = *(const bf16x8*)&U.s.Ps[w][l15 * 72 + c * 32 + quad * 8];
#pragma unroll
        for (int d = 0; d < 4; d++) {
          bf16x8 vb = *(const bf16x8*)&VT[(d * 16 + l15) * 72 + c * 32 + quad * 8];
          Of[d] = __builtin_amdgcn_mfma_f32_16x16x32_bf16(pa, vb, Of[d], 0, 0, 0);
        }
      }
      __builtin_amdgcn_s_setprio(0);
    }

#pragma unroll
    for (int d = 0; d < 4; d++)
#pragma unroll
      for (int r = 0; r < 4; r++) {
        int qi = i0 + w * 16 + quad * 4 + r;
        sout[(size_t)qi * DIMM + h * HD + d * 16 + l15] = Of[d][r] / lrow[r];
      }
  }
}

// ---------- fused: compressed attention + top-8 + fine attention (in-wave sel) ----------
// 4 q-rows/block, one row per wave; rank-based top-8 (replaces serial shuffle butterfly).
__global__ void __launch_bounds__(256)
k_cmpf(const float* __restrict__ qg, const float* __restrict__ ckb,
       const float* __restrict__ cvb, const float* __restrict__ k_mem,
       const float* __restrict__ v_mem, const ushort* __restrict__ khm_h,
       const ushort* __restrict__ vhm_h, float* __restrict__ cout,
       float* __restrict__ fout) {
  int h = blockIdx.y, i0 = blockIdx.x * 4;
  int tid = threadIdx.x, lane = tid & 63, w = tid >> 6;
  __shared__ float ckt[64][65];
  __shared__ float cvs[64][65];
  __shared__ float qs[4][64];
  __shared__ float kms[64], vms[64];
  __shared__ float sp[4][64];
  __shared__ float ivs[4][64];    // impv values for rank selection
  __shared__ int   sels[4][8];    // rank -> selected block index
  __shared__ float spf[4][144];   // fine p values, per wave

#pragma unroll
  for (int r = 0; r < 4; r++) {
    int f = r * 256 + tid;
    int c = f >> 4, d0 = (f & 15) * 4;
    float4 t = *(const float4*)(ckb + ((size_t)h * 64 + c) * 64 + d0);
    ckt[d0][c] = t.x; ckt[d0 + 1][c] = t.y; ckt[d0 + 2][c] = t.z; ckt[d0 + 3][c] = t.w;
    float4 u = *(const float4*)(cvb + ((size_t)h * 64 + c) * 64 + d0);
    cvs[c][d0] = u.x; cvs[c][d0 + 1] = u.y; cvs[c][d0 + 2] = u.z; cvs[c][d0 + 3] = u.w;
  }
  if (tid < 64) {
    int r = tid >> 4, d0 = (tid & 15) * 4;
    float4 t = *(const float4*)(qg + (size_t)(i0 + r) * DIMM + h * HD + d0);
    qs[r][d0] = t.x; qs[r][d0 + 1] = t.y; qs[r][d0 + 2] = t.z; qs[r][d0 + 3] = t.w;
  } else if (tid < 128) {
    kms[tid - 64] = k_mem[h * HD + tid - 64];
  } else if (tid < 192) {
    vms[tid - 128] = v_mem[h * HD + tid - 128];
  }
  __syncthreads();

  const ushort* kbase = khm_h + (size_t)h * 65536;
  const ushort* vbase = vhm_h + (size_t)h * 65536;

  int qi = i0 + w;   // one row per wave
  {
    // ===== compressed attention (split chains) =====
    float d0a = 0.f, d1a = 0.f, d2a = 0.f, d3a = 0.f;
    float m0a = 0.f, m1a = 0.f, m2a = 0.f, m3a = 0.f;
#pragma unroll
    for (int e = 0; e < 64; e += 4) {
      d0a = fmaf(qs[w][e],     ckt[e][lane],     d0a);
      d1a = fmaf(qs[w][e + 1], ckt[e + 1][lane], d1a);
      d2a = fmaf(qs[w][e + 2], ckt[e + 2][lane], d2a);
      d3a = fmaf(qs[w][e + 3], ckt[e + 3][lane], d3a);
      m0a = fmaf(qs[w][e],     kms[e],     m0a);
      m1a = fmaf(qs[w][e + 1], kms[e + 1], m1a);
      m2a = fmaf(qs[w][e + 2], kms[e + 2], m2a);
      m3a = fmaf(qs[w][e + 3], kms[e + 3], m3a);
    }
    float dot = (d0a + d1a) + (d2a + d3a);
    float dm  = (m0a + m1a) + (m2a + m3a);
    bool vis = (lane * BCB + BCB - 1) < qi;
    float sj = vis ? dot * SCALE : NEGV;
    float smem = dm * SCALE;
    float m = wred_max(fmaxf(sj, smem));
    float p = expf(sj - m);
    float pmem = expf(smem - m);
    float l = wred_sum(p) + pmem;
    float inv = 1.f / l;

    // ===== rank-based top-8: order = (value desc, index asc), same as butterfly =====
    float impv = vis ? p : NEGV;
    ivs[w][lane] = impv;
    sp[w][lane] = p;
    // wave-internal LDS write->read; lockstep wave64, compiler inserts lgkmcnt
    int r0 = 0, r1 = 0, r2 = 0, r3 = 0;
#pragma unroll
    for (int j = 0; j < 64; j += 4) {
      float v0 = ivs[w][j],     v1 = ivs[w][j + 1];
      float v2 = ivs[w][j + 2], v3 = ivs[w][j + 3];
      r0 += (v0 > impv || (v0 == impv && (j)     < lane)) ? 1 : 0;
      r1 += (v1 > impv || (v1 == impv && (j + 1) < lane)) ? 1 : 0;
      r2 += (v2 > impv || (v2 == impv && (j + 2) < lane)) ? 1 : 0;
      r3 += (v3 > impv || (v3 == impv && (j + 3) < lane)) ? 1 : 0;
    }
    int rank = (r0 + r1) + (r2 + r3);
    if (rank < KSEL) sels[w][rank] = (impv >= 0.f) ? lane : -1;

    float o0 = pmem * vms[lane], o1 = 0.f, o2 = 0.f, o3 = 0.f;
#pragma unroll
    for (int j = 0; j < 64; j += 4) {
      o0 = fmaf(sp[w][j],     cvs[j][lane],     o0);
      o1 = fmaf(sp[w][j + 1], cvs[j + 1][lane], o1);
      o2 = fmaf(sp[w][j + 2], cvs[j + 2][lane], o2);
      o3 = fmaf(sp[w][j + 3], cvs[j + 3][lane], o3);
    }
    float od = (o0 + o1) + (o2 + o3);
    cout[(size_t)qi * DIMM + h * HD + lane] = od * inv;

    // ===== fine attention for row qi (sel read from per-wave LDS) =====
    int own = qi >> 4;
    float slv[3];
#pragma unroll
    for (int t = 0; t < 3; t++) {
      int key = t * 64 + lane;
      float sv = NEGV;
      if (key < 144) {
        int kk = key >> 4, krow = key & 15;
        int bidx; bool fvis;
        if (kk < KSEL) {
          bidx = sels[w][kk];
          fvis = (bidx >= 0);
          if (!fvis) bidx = 0;
        } else {
          bidx = own;
          fvis = (krow <= (qi & 15));
        }
        const ushort* kr = kbase + (size_t)(bidx * BSB + krow) * 64;
        float f0 = 0.f, f1 = 0.f, f2 = 0.f, f3 = 0.f;
#pragma unroll
        for (int e8 = 0; e8 < 8; e8++) {
          ushort kv8[8];
          *(int4*)kv8 = *(const int4*)(kr + e8 * 8);
          f0 = fmaf(qs[w][e8 * 8 + 0], b2f(kv8[0]), f0);
          f1 = fmaf(qs[w][e8 * 8 + 1], b2f(kv8[1]), f1);
          f2 = fmaf(qs[w][e8 * 8 + 2], b2f(kv8[2]), f2);
          f3 = fmaf(qs[w][e8 * 8 + 3], b2f(kv8[3]), f3);
          f0 = fmaf(qs[w][e8 * 8 + 4], b2f(kv8[4]), f0);
          f1 = fmaf(qs[w][e8 * 8 + 5], b2f(kv8[5]), f1);
          f2 = fmaf(qs[w][e8 * 8 + 6], b2f(kv8[6]), f2);
          f3 = fmaf(qs[w][e8 * 8 + 7], b2f(kv8[7]), f3);
        }
        float fd = (f0 + f1) + (f2 + f3);
        sv = fvis ? fd * SCALE : NEGV;
      }
      slv[t] = sv;
    }
    float fm = wred_max(fmaxf(fmaxf(slv[0], slv[1]), slv[2]));
    float fsum = 0.f;
#pragma unroll
    for (int t = 0; t < 3; t++) {
      int key = t * 64 + lane;
      if (key < 144) {
        float pv = expf(slv[t] - fm);
        spf[w][key] = pv;
        fsum += pv;
      }
    }
    fsum = wred_sum(fsum);
    float finv = 1.f / fsum;

    float a0 = 0.f, a1 = 0.f, a2 = 0.f, a3 = 0.f;
#pragma unroll
    for (int kk = 0; kk < KSEL + 1; kk++) {
      int bidx = (kk < KSEL) ? sels[w][kk] : own;
      if (bidx < 0) bidx = 0;
      const ushort* vr = vbase + (size_t)(bidx * BSB) * 64 + lane;
#pragma unroll
      for (int krow = 0; krow < 16; krow += 4) {
        a0 = fmaf(spf[w][kk * 16 + krow],     b2f(vr[(size_t)(krow) * 64]),     a0);
        a1 = fmaf(spf[w][kk * 16 + krow + 1], b2f(vr[(size_t)(krow + 1) * 64]), a1);
        a2 = fmaf(spf[w][kk * 16 + krow + 2], b2f(vr[(size_t)(krow + 2) * 64]), a2);
        a3 = fmaf(spf[w][kk * 16 + krow + 3], b2f(vr[(size_t)(krow + 3) * 64]), a3);
      }
    }
    float facc = (a0 + a1) + (a2 + a3);
    fout[(size_t)qi * DIMM + h * HD + lane] = facc * finv;
  }
}

extern "C" void kernel_launch(void* const* d_in, const int* in_sizes, int n_in,
                              void* d_out, int out_size, void* d_ws, size_t ws_size,
                              hipStream_t stream) {
  const float* x     = (const float*)d_in[0];
  const float* ve    = (const float*)d_in[1]; (void)ve;
  const float* x0    = (const float*)d_in[2];
  const float* lam   = (const float*)d_in[3];
  const float* Wq    = (const float*)d_in[4];
  const float* Wk    = (const float*)d_in[5];
  const float* Wv    = (const float*)d_in[6];
  const float* Wo    = (const float*)d_in[7];
  const float* Wg    = (const float*)d_in[8];
  const float* k_pos = (const float*)d_in[9];
  const float* v_pos = (const float*)d_in[10];
  const float* Wck   = (const float*)d_in[11];
  const float* bck   = (const float*)d_in[12];
  const float* Wcv   = (const float*)d_in[13];
  const float* bcv   = (const float*)d_in[14];
  const float* k_mem = (const float*)d_in[15];
  const float* v_mem = (const float*)d_in[16];
  const float* W1    = (const float*)d_in[17];
  const float* W2    = (const float*)d_in[18];
  float* out = (float*)d_out;
  float* ws  = (float*)d_ws;

  const size_t NW = (size_t)NTOK * DIMM;   // 524288
  float* xr    = ws;              // f32 residual (read by rms_bf)
  float* xn    = ws + 1 * NW;     // xnh/xnl bf16 planes (dead after qkv)
  float* q     = ws + 2 * NW;     // q f32; later Wo partial p1w, then h1b (lower)
  float* kslot = ws + 3 * NW;     // khm_h/khm_l bf16; later p0w, then h1b (upper)
  float* vslot = ws + 4 * NW;     // vhm_h/vhm_l bf16
  float* coutb = ws + 5 * NW;
  float* foutb = ws + 6 * NW;
  float* soutb = ws + 7 * NW;     // later: ybf (bf16 overlay)
  float* gates = ws + 9 * NW;
  float* ckb   = gates + 32768;
  float* cvb   = ckb + 32768;
  ushort* qkvTh = (ushort*)(cvb + 32768 + 65536);
  ushort* qkvTl = qkvTh + 1600 * 512;
  ushort* WoT   = qkvTl + 1600 * 512;
  ushort* W1T   = WoT   + 512 * 512;
  ushort* W2T   = W1T   + 2048 * 512;
  ushort* WckTh = W2T   + 512 * 2048;
  ushort* WckTl = WckTh + 64 * 1024;
  ushort* WcvTh = WckTl + 64 * 1024;
  ushort* WcvTl = WcvTh + 64 * 1024;
  float* ctab   = (float*)(WcvTl + 64 * 1024);  // 1024 x 32
  float* stab   = ctab + 32768;
  float* pwk    = stab + 32768;                 // 8 x 64 (pos@Wck + bck)
  float* pwv    = pwk + 512;

  ushort* xnh = (ushort*)xn;          // bf16 hi plane of rms(x)
  ushort* xnl = xnh + NW;             // bf16 lo plane
  ushort* khm_h = (ushort*)kslot;     // rope'd k, head-major, bf16 hi
  ushort* khm_l = khm_h + 524288;     // lo
  ushort* vhm_h = (ushort*)vslot;     // v head-major bf16 hi
  ushort* vhm_l = vhm_h + 524288;     // lo
  float* p0w = kslot;                 // Wo split-K partials (k/v mirrors dead after cmpf)
  float* p1w = q;
  ushort* ybf = (ushort*)soutb;       // bf16 y (soutb dead after wo)
  ushort* h1b = (ushort*)q;           // bf16 h1 (slots 2-3, after rms_bf read p's)

  WtrPack pk;
  pk.d[0] = {Wq, qkvTh,              qkvTl,              512, 512,  512};
  pk.d[1] = {Wk, qkvTh + 512 * 512,  qkvTl + 512 * 512,  512, 512,  512};
  pk.d[2] = {Wv, qkvTh + 1024 * 512, qkvTl + 1024 * 512, 512, 512,  512};
  pk.d[3] = {Wo, WoT, nullptr,  512, 512,  512};
  pk.d[4] = {W1, W1T, nullptr,  512, 2048, 2048};
  pk.d[5] = {W2, W2T, nullptr, 2048, 512,  512};
  pk.d[6] = {Wck, WckTh, WckTl, 1024, 64, 64};
  pk.d[7] = {Wcv, WcvTh, WcvTl, 1024, 64, 64};
  pk.d[8] = {Wg, qkvTh + 1536 * 512, qkvTl + 1536 * 512, 512, 24, 64};
  int cum = 0;
  for (int e = 0; e < 9; e++) {
    cum += (pk.d[e].Npad / 32) * (pk.d[e].K / 32);
    pk.cum[e] = cum;
  }

  // roots: transposes + resid/rms + trig tables + pos@W, one launch
  k_pre<<<cum + NTOK + 128 + 16, 256, 0, stream>>>(
      pk, x, x0, lam, xr, xnh, xnl, ctab, stab,
      k_pos, v_pos, Wck, Wcv, bck, bcv, pwk, pwv);

  // QKV GEMM 128x64 tiles with fused RoPE + bf16 hi/lo k/v mirrors
  k_gemm_qkv<<<dim3(25, NTOK / 128), 256, 0, stream>>>(
      xnh, xnl, qkvTh, qkvTl, q, khm_h, khm_l, vhm_h, vhm_l, gates,
      ctab, stab);

  // merged: ckcv (32 blocks) || swin (128 blocks)
  k_mid<<<160, 256, 0, stream>>>(khm_h, khm_l, vhm_h, vhm_l,
                                 WckTh, WckTl, WcvTh, WcvTl,
                                 pwk, pwv, ckb, cvb, q, soutb);

  // fused cmp + top-8(rank) + fine; 4 rows/block, 1 row/wave -> 2048 blocks
  k_cmpf<<<dim3(NTOK / 4, NH), 256, 0, stream>>>(
      q, ckb, cvb, k_mem, v_mem, khm_h, vhm_h, coutb, foutb);

  // Wo split-K=2 with prefetched gated combine; combine folded into rms_bf
  k_gemm_wo<<<dim3(512 / 64, NTOK / 64, 2), 256, 0, stream>>>(
      coutb, foutb, soutb, gates, WoT, p0w, p1w);
  // rms_bf pre-fills out with x2; W2 atomically accumulates on top
  k_rms_bf<<<NTOK, 256, 0, stream>>>(xr, p0w, p1w, out, ybf);

  k_gemm_w1<<<dim3(2048 / 64, NTOK / 128), 256, 0, stream>>>(ybf, W1T, h1b);
  k_gemm_w2<<<dim3(512 / 64, NTOK / 64, 2), 256, 0, stream>>>(h1b, W2T, out);
}